// Round 1
// baseline (930.168 us; speedup 1.0000x reference)
//
#include <hip/hip_runtime.h>
#include <hip/hip_bf16.h>

// ---- problem constants ----
#define B_     16
#define NFEAT  16
#define TLEN   64
#define SCL    32
#define HID_   128
#define FS_    4
#define NH_    2
#define DH_    64
#define H1_    61
#define W1_    29
#define H2_    58
#define W2_    26
#define L_     1508     // 58*26
#define U_     40       // 5*ceil(ln(1508)) = 40
#define M1_    28304    // B*H1*W1
#define M2_    24128    // B*L

// ======================================================================
// small prep kernels
// ======================================================================

// x (B,16,64,32) -> xp (B,64,32,16) channel-last
__global__ __launch_bounds__(256) void xpose_x(const float* __restrict__ x,
                                               float* __restrict__ xp) {
    int idx = blockIdx.x * 256 + threadIdx.x;           // coalesced read
    if (idx >= B_ * NFEAT * TLEN * SCL) return;
    int xx = idx & 31; int t = idx >> 5;
    int y  = t & 63;   t >>= 6;
    int ic = t & 15;   int b = t >> 4;
    xp[(((b * TLEN + y) * SCL + xx) * NFEAT) + ic] = x[idx];
}

// conv1_w (co,ic,fy,fx) -> w1m[k][co], k = (fy*4+fx)*16+ic
__global__ __launch_bounds__(256) void prep_w1(const float* __restrict__ w,
                                               float* __restrict__ wm) {
    int idx = blockIdx.x * 256 + threadIdx.x;
    if (idx >= 256 * 128) return;
    int co = idx & 127; int k = idx >> 7;
    int ic = k & 15; int s = k >> 4; int fy = s >> 2, fx = s & 3;
    wm[idx] = w[((co * NFEAT + ic) * FS_ + fy) * FS_ + fx];
}

// conv2_w (co,ic,fy,fx) -> w2m[k][co], k = (fy*4+fx)*128+ic
__global__ __launch_bounds__(256) void prep_w2(const float* __restrict__ w,
                                               float* __restrict__ wm) {
    int idx = blockIdx.x * 256 + threadIdx.x;
    if (idx >= 2048 * 128) return;
    int co = idx & 127; int k = idx >> 7;
    int ic = k & 127; int s = k >> 7; int fy = s >> 2, fx = s & 3;
    wm[idx] = w[((co * HID_ + ic) * FS_ + fy) * FS_ + fx];
}

// ======================================================================
// tiled fp32 GEMM: C[M x 128] = op(A)[M x K] @ Bm[K x 128] + bias
// BM=64, BN=64, BK=32, 256 threads, 4x4 acc per thread.
// ASRC: 0 = A row-major MxK; 1 = implicit im2col from channel-last conv input
// OSTORE: 0 = C[m*128+n]; 1 = QKV scatter to (b, h, l, d)
// ======================================================================
template <int ASRC, int OSTORE, bool RELU, int CIN, int HIN, int WIN, int HOUT, int WOUT>
__global__ __launch_bounds__(256) void gemm_k(const float* __restrict__ A,
                                              const float* __restrict__ Bm,
                                              const float* __restrict__ bias,
                                              float* __restrict__ C,
                                              int Mrows, int K) {
    __shared__ float As[32][68];   // [k][m], padded: 68*4B = 272B (16B-aligned rows)
    __shared__ float Bs[32][68];   // [k][n]
    const int tid = threadIdx.x;
    const int tx = tid & 15, ty = tid >> 4;
    const int m0 = blockIdx.x * 64;
    const int n0 = blockIdx.y * 64;

    float acc[4][4] = {};

    for (int k0 = 0; k0 < K; k0 += 32) {
        // ---- load B tile: 2 float4 per thread ----
#pragma unroll
        for (int i = 0; i < 2; ++i) {
            int s = tid + i * 256;            // 0..511 float4 slots
            int kk = s >> 4, n4 = s & 15;
            float4 v = *(const float4*)&Bm[(size_t)(k0 + kk) * 128 + n0 + n4 * 4];
            *(float4*)&Bs[kk][n4 * 4] = v;
        }
        // ---- load A tile (transposed into LDS): 2 float4 per thread ----
#pragma unroll
        for (int i = 0; i < 2; ++i) {
            int s = tid + i * 256;
            int row = s >> 3, kq = s & 7;
            int m = m0 + row;
            if (m >= Mrows) m = Mrows - 1;    // clamp: garbage rows never stored
            int k = k0 + kq * 4;
            const float* src;
            if constexpr (ASRC == 0) {
                src = &A[(size_t)m * K + k];
            } else {
                int bb = m / (HOUT * WOUT), r = m % (HOUT * WOUT);
                int y = r / WOUT, xx = r % WOUT;
                int slice = k / CIN, ic = k - slice * CIN;
                int fy = slice / FS_, fx = slice % FS_;
                src = &A[(size_t)(((bb * HIN + y + fy) * WIN) + (xx + fx)) * CIN + ic];
            }
            float4 v = *(const float4*)src;
            As[kq * 4 + 0][row] = v.x;
            As[kq * 4 + 1][row] = v.y;
            As[kq * 4 + 2][row] = v.z;
            As[kq * 4 + 3][row] = v.w;
        }
        __syncthreads();
        // ---- compute ----
#pragma unroll
        for (int k = 0; k < 32; ++k) {
            float4 av = *(const float4*)&As[k][ty * 4];
            float4 bv = *(const float4*)&Bs[k][tx * 4];
            float a_[4] = {av.x, av.y, av.z, av.w};
            float b_[4] = {bv.x, bv.y, bv.z, bv.w};
#pragma unroll
            for (int i = 0; i < 4; ++i)
#pragma unroll
                for (int j = 0; j < 4; ++j)
                    acc[i][j] = fmaf(a_[i], b_[j], acc[i][j]);
        }
        __syncthreads();
    }

    // ---- epilogue ----
    float bb4[4];
#pragma unroll
    for (int j = 0; j < 4; ++j) bb4[j] = bias[n0 + tx * 4 + j];
#pragma unroll
    for (int i = 0; i < 4; ++i) {
        int m = m0 + ty * 4 + i;
        if (m >= Mrows) continue;
        float4 v;
        float* vp = (float*)&v;
#pragma unroll
        for (int j = 0; j < 4; ++j) {
            float t = acc[i][j] + bb4[j];
            if (RELU) t = fmaxf(t, 0.f);
            vp[j] = t;
        }
        if constexpr (OSTORE == 0) {
            *(float4*)&C[(size_t)m * 128 + n0 + tx * 4] = v;
        } else {
            int b = m / L_, l = m - b * L_;
            int h = n0 >> 6;                  // BN=64 aligns with the head split
            *(float4*)&C[(((size_t)(b * NH_ + h) * L_ + l) << 6) + tx * 4] = v;
        }
    }
}

// ======================================================================
// M[b,h,l] = max_u(q . K[idx[l,u]]) - sum_u(...)/L      (one wave per l)
// ======================================================================
__global__ __launch_bounds__(256) void probscore_k(const float* __restrict__ Q,
                                                   const float* __restrict__ Kt,
                                                   const int* __restrict__ idxs,
                                                   float* __restrict__ Mout) {
    int w = threadIdx.x >> 6, lane = threadIdx.x & 63;
    int gl = blockIdx.x * 4 + w;              // (b*NH+h)*L + l
    if (gl >= B_ * NH_ * L_) return;
    int bh = gl / L_, l = gl - bh * L_;
    float q = Q[((size_t)bh * L_ + l) * 64 + lane];
    const float* Kb = Kt + (size_t)bh * L_ * 64;
    float mx = -1e30f, sm = 0.f;
    for (int u = 0; u < U_; ++u) {
        int idx = idxs[l * U_ + u];
        float p = q * Kb[idx * 64 + lane];
#pragma unroll
        for (int o = 32; o >= 1; o >>= 1) p += __shfl_xor(p, o);
        mx = fmaxf(mx, p);
        sm += p;
    }
    if (lane == 0) Mout[bh * L_ + l] = mx - sm / (float)L_;
}

// ======================================================================
// top-U indices of M per (b,h); JAX tie-break: equal value -> lower index
// ======================================================================
__global__ __launch_bounds__(256) void topk_k(const float* __restrict__ Mv,
                                              int* __restrict__ Mtop) {
    __shared__ float sv[L_];
    __shared__ float rv[256];
    __shared__ int ri[256];
    int bh = blockIdx.x, t = threadIdx.x;
    for (int i = t; i < L_; i += 256) sv[i] = Mv[bh * L_ + i];
    __syncthreads();
    for (int it = 0; it < U_; ++it) {
        float bv = -1e30f; int bi = 1 << 30;
        for (int i = t; i < L_; i += 256) {
            float v = sv[i];
            if (v > bv || (v == bv && i < bi)) { bv = v; bi = i; }
        }
        rv[t] = bv; ri[t] = bi;
        __syncthreads();
        for (int s = 128; s >= 1; s >>= 1) {
            if (t < s) {
                float v2 = rv[t + s]; int i2 = ri[t + s];
                if (v2 > rv[t] || (v2 == rv[t] && i2 < ri[t])) { rv[t] = v2; ri[t] = i2; }
            }
            __syncthreads();
        }
        if (t == 0) { Mtop[bh * U_ + it] = ri[0]; sv[ri[0]] = -1e30f; }
        __syncthreads();
    }
}

// ======================================================================
// Vmean[b,h,d] = mean_l V[b,h,l,d]
// ======================================================================
__global__ __launch_bounds__(256) void vmean_k(const float* __restrict__ V,
                                               float* __restrict__ Vm) {
    __shared__ float red[256];
    int bh = blockIdx.x;
    int d = threadIdx.x & 63, part = threadIdx.x >> 6;
    const float* Vb = V + (size_t)bh * L_ * 64;
    float s = 0.f;
    for (int l = part; l < L_; l += 4) s += Vb[l * 64 + d];
    red[threadIdx.x] = s;
    __syncthreads();
    if (part == 0) {
        s = red[d] + red[64 + d] + red[128 + d] + red[192 + d];
        Vm[bh * 64 + d] = s / (float)L_;
    }
}

// ctxp[b][l][h*64+d] = Vmean[b][h][d]   (float4 grid-stride fill)
__global__ __launch_bounds__(256) void fill_ctx_k(const float* __restrict__ Vm,
                                                  float* __restrict__ ctxp) {
    int idx = blockIdx.x * 256 + threadIdx.x;     // float4 index
    if (idx >= B_ * L_ * 32) return;
    int c4 = idx & 31;
    int bl = idx >> 5;
    int b = bl / L_;
    int h = c4 >> 4, d4 = (c4 & 15) * 4;
    float4 v = *(const float4*)&Vm[(b * 2 + h) * 64 + d4];
    *(float4*)&ctxp[(size_t)idx * 4] = v;
}

// ======================================================================
// one block per (b,h,u): scores row -> softmax -> PV -> scatter into ctxp
// ======================================================================
__global__ __launch_bounds__(256) void attn_k(const float* __restrict__ Q,
                                              const float* __restrict__ Kt,
                                              const float* __restrict__ V,
                                              const int* __restrict__ Mtop,
                                              float* __restrict__ ctxp) {
    __shared__ float s[L_];
    __shared__ float red[256];
    int bhu = blockIdx.x;
    int u = bhu % U_, bh = bhu / U_;
    int b = bh >> 1, h = bh & 1;
    int qi = Mtop[bh * U_ + u];
    int w = threadIdx.x >> 6, lane = threadIdx.x & 63;

    const float* Kb = Kt + (size_t)bh * L_ * 64;
    float q = Q[((size_t)bh * L_ + qi) * 64 + lane];
    float mx = -1e30f;
    for (int l = w; l < L_; l += 4) {
        float p = q * Kb[l * 64 + lane];
#pragma unroll
        for (int o = 32; o >= 1; o >>= 1) p += __shfl_xor(p, o);
        p *= 0.125f;                      // 1/sqrt(64)
        if (lane == 0) s[l] = p;
        mx = fmaxf(mx, p);
    }
    red[threadIdx.x] = mx;
    __syncthreads();
    float bmx = fmaxf(fmaxf(red[0], red[64]), fmaxf(red[128], red[192]));

    float ps = 0.f;
    for (int l = threadIdx.x; l < L_; l += 256) {
        float e = __expf(s[l] - bmx);
        s[l] = e;
        ps += e;
    }
    red[threadIdx.x] = ps;
    __syncthreads();
    for (int st = 128; st >= 1; st >>= 1) {
        if (threadIdx.x < st) red[threadIdx.x] += red[threadIdx.x + st];
        __syncthreads();
    }
    float inv = 1.0f / red[0];

    const float* Vb = V + (size_t)bh * L_ * 64;
    float acc = 0.f;
    for (int l = w; l < L_; l += 4) acc += s[l] * Vb[l * 64 + lane];
    __syncthreads();
    red[threadIdx.x] = acc;
    __syncthreads();
    if (w == 0) {
        acc = red[lane] + red[64 + lane] + red[128 + lane] + red[192 + lane];
        ctxp[((size_t)b * L_ + qi) * 128 + h * 64 + lane] = acc * inv;
    }
}

// ======================================================================
// launch
// ======================================================================
extern "C" void kernel_launch(void* const* d_in, const int* in_sizes, int n_in,
                              void* d_out, int out_size, void* d_ws, size_t ws_size,
                              hipStream_t stream) {
    const float* x   = (const float*)d_in[0];
    const float* c1w = (const float*)d_in[1];
    const float* c1b = (const float*)d_in[2];
    const float* c2w = (const float*)d_in[3];
    const float* c2b = (const float*)d_in[4];
    const float* wq  = (const float*)d_in[5];
    const float* bq  = (const float*)d_in[6];
    const float* wk  = (const float*)d_in[7];
    const float* bk  = (const float*)d_in[8];
    const float* wv  = (const float*)d_in[9];
    const float* bv  = (const float*)d_in[10];
    const float* wo  = (const float*)d_in[11];
    const float* bo  = (const float*)d_in[12];
    const int* isamp = (const int*)d_in[13];
    float* out = (float*)d_out;

    float* ws   = (float*)d_ws;
    float* xp   = ws;                    // 524288
    float* w1m  = xp   + 524288;         // 32768
    float* w2m  = w1m  + 32768;          // 262144
    float* h1p  = w2m  + 262144;         // 3622912  (B,61,29,128) channel-last
    float* seq  = h1p  + 3622912;        // 3088384  (B,L,128)
    float* Q    = seq  + 3088384;        // 3088384  (B,NH,L,64)
    float* Kt   = Q    + 3088384;        // 3088384
    float* V    = Kt   + 3088384;        // 3088384
    float* Mb   = V    + 3088384;        // 48256
    float* Vm   = Mb   + 48256;          // 2048
    float* ctxp = Vm   + 2048;           // 3088384  (B,L,128)
    int*   Mtop = (int*)(ctxp + 3088384);// 1280 ints

    xpose_x<<<2048, 256, 0, stream>>>(x, xp);
    prep_w1<<<128, 256, 0, stream>>>(c1w, w1m);
    prep_w2<<<1024, 256, 0, stream>>>(c2w, w2m);

    // conv1: implicit im2col, M=28304, K=256, ReLU -> h1p
    gemm_k<1, 0, true, 16, 64, 32, 61, 29>
        <<<dim3(443, 2), 256, 0, stream>>>(xp, w1m, c1b, h1p, M1_, 256);
    // conv2: implicit im2col, M=24128, K=2048, ReLU -> seq
    gemm_k<1, 0, true, 128, 61, 29, 58, 26>
        <<<dim3(377, 2), 256, 0, stream>>>(h1p, w2m, c2b, seq, M2_, 2048);

    // Q/K/V projections with (b,h,l,d) scatter
    gemm_k<0, 1, false, 1, 1, 1, 1, 1>
        <<<dim3(377, 2), 256, 0, stream>>>(seq, wq, bq, Q, M2_, 128);
    gemm_k<0, 1, false, 1, 1, 1, 1, 1>
        <<<dim3(377, 2), 256, 0, stream>>>(seq, wk, bk, Kt, M2_, 128);
    gemm_k<0, 1, false, 1, 1, 1, 1, 1>
        <<<dim3(377, 2), 256, 0, stream>>>(seq, wv, bv, V, M2_, 128);

    probscore_k<<<12064, 256, 0, stream>>>(Q, Kt, isamp, Mb);
    topk_k<<<32, 256, 0, stream>>>(Mb, Mtop);
    vmean_k<<<32, 256, 0, stream>>>(V, Vm);
    fill_ctx_k<<<3016, 256, 0, stream>>>(Vm, ctxp);
    attn_k<<<1280, 256, 0, stream>>>(Q, Kt, V, Mtop, ctxp);

    // out = ctxp @ wo + bo
    gemm_k<0, 0, false, 1, 1, 1, 1, 1>
        <<<dim3(377, 2), 256, 0, stream>>>(ctxp, wo, bo, out, M2_, 128);
}

// Round 2
// 919.872 us; speedup vs baseline: 1.0112x; 1.0112x over previous
//
#include <hip/hip_runtime.h>
#include <hip/hip_bf16.h>

// ---- problem constants ----
#define B_     16
#define NFEAT  16
#define TLEN   64
#define SCL    32
#define HID_   128
#define FS_    4
#define NH_    2
#define DH_    64
#define H1_    61
#define W1_    29
#define H2_    58
#define W2_    26
#define L_     1508     // 58*26
#define L4_    377      // L/4
#define U_     40       // 5*ceil(ln(1508))
#define M1_    28304    // B*H1*W1
#define M2_    24128    // B*L
#define GL_    48256    // B*NH*L

// ======================================================================
// small prep kernels
// ======================================================================

__global__ __launch_bounds__(256) void xpose_x(const float* __restrict__ x,
                                               float* __restrict__ xp) {
    int idx = blockIdx.x * 256 + threadIdx.x;
    if (idx >= B_ * NFEAT * TLEN * SCL) return;
    int xx = idx & 31; int t = idx >> 5;
    int y  = t & 63;   t >>= 6;
    int ic = t & 15;   int b = t >> 4;
    xp[(((b * TLEN + y) * SCL + xx) * NFEAT) + ic] = x[idx];
}

__global__ __launch_bounds__(256) void prep_w1(const float* __restrict__ w,
                                               float* __restrict__ wm) {
    int idx = blockIdx.x * 256 + threadIdx.x;
    if (idx >= 256 * 128) return;
    int co = idx & 127; int k = idx >> 7;
    int ic = k & 15; int s = k >> 4; int fy = s >> 2, fx = s & 3;
    wm[idx] = w[((co * NFEAT + ic) * FS_ + fy) * FS_ + fx];
}

__global__ __launch_bounds__(256) void prep_w2(const float* __restrict__ w,
                                               float* __restrict__ wm) {
    int idx = blockIdx.x * 256 + threadIdx.x;
    if (idx >= 2048 * 128) return;
    int co = idx & 127; int k = idx >> 7;
    int ic = k & 127; int s = k >> 7; int fy = s >> 2, fx = s & 3;
    wm[idx] = w[((co * HID_ + ic) * FS_ + fy) * FS_ + fx];
}

// ======================================================================
// tiled fp32 GEMM (unchanged from R1)
// ======================================================================
template <int ASRC, int OSTORE, bool RELU, int CIN, int HIN, int WIN, int HOUT, int WOUT>
__global__ __launch_bounds__(256) void gemm_k(const float* __restrict__ A,
                                              const float* __restrict__ Bm,
                                              const float* __restrict__ bias,
                                              float* __restrict__ C,
                                              int Mrows, int K) {
    __shared__ float As[32][68];
    __shared__ float Bs[32][68];
    const int tid = threadIdx.x;
    const int tx = tid & 15, ty = tid >> 4;
    const int m0 = blockIdx.x * 64;
    const int n0 = blockIdx.y * 64;

    float acc[4][4] = {};

    for (int k0 = 0; k0 < K; k0 += 32) {
#pragma unroll
        for (int i = 0; i < 2; ++i) {
            int s = tid + i * 256;
            int kk = s >> 4, n4 = s & 15;
            float4 v = *(const float4*)&Bm[(size_t)(k0 + kk) * 128 + n0 + n4 * 4];
            *(float4*)&Bs[kk][n4 * 4] = v;
        }
#pragma unroll
        for (int i = 0; i < 2; ++i) {
            int s = tid + i * 256;
            int row = s >> 3, kq = s & 7;
            int m = m0 + row;
            if (m >= Mrows) m = Mrows - 1;
            int k = k0 + kq * 4;
            const float* src;
            if constexpr (ASRC == 0) {
                src = &A[(size_t)m * K + k];
            } else {
                int bb = m / (HOUT * WOUT), r = m % (HOUT * WOUT);
                int y = r / WOUT, xx = r % WOUT;
                int slice = k / CIN, ic = k - slice * CIN;
                int fy = slice / FS_, fx = slice % FS_;
                src = &A[(size_t)(((bb * HIN + y + fy) * WIN) + (xx + fx)) * CIN + ic];
            }
            float4 v = *(const float4*)src;
            As[kq * 4 + 0][row] = v.x;
            As[kq * 4 + 1][row] = v.y;
            As[kq * 4 + 2][row] = v.z;
            As[kq * 4 + 3][row] = v.w;
        }
        __syncthreads();
#pragma unroll
        for (int k = 0; k < 32; ++k) {
            float4 av = *(const float4*)&As[k][ty * 4];
            float4 bv = *(const float4*)&Bs[k][tx * 4];
            float a_[4] = {av.x, av.y, av.z, av.w};
            float b_[4] = {bv.x, bv.y, bv.z, bv.w};
#pragma unroll
            for (int i = 0; i < 4; ++i)
#pragma unroll
                for (int j = 0; j < 4; ++j)
                    acc[i][j] = fmaf(a_[i], b_[j], acc[i][j]);
        }
        __syncthreads();
    }

    float bb4[4];
#pragma unroll
    for (int j = 0; j < 4; ++j) bb4[j] = bias[n0 + tx * 4 + j];
#pragma unroll
    for (int i = 0; i < 4; ++i) {
        int m = m0 + ty * 4 + i;
        if (m >= Mrows) continue;
        float4 v;
        float* vp = (float*)&v;
#pragma unroll
        for (int j = 0; j < 4; ++j) {
            float t = acc[i][j] + bb4[j];
            if (RELU) t = fmaxf(t, 0.f);
            vp[j] = t;
        }
        if constexpr (OSTORE == 0) {
            *(float4*)&C[(size_t)m * 128 + n0 + tx * 4] = v;
        } else {
            int b = m / L_, l = m - b * L_;
            int h = n0 >> 6;
            *(float4*)&C[(((size_t)(b * NH_ + h) * L_ + l) << 6) + tx * 4] = v;
        }
    }
}

// ======================================================================
// K transpose: Kt[bh][l][d] -> Kdt[bh][d][l]   (32x32 LDS tiles)
// grid (48, 2, 32), block 256
// ======================================================================
__global__ __launch_bounds__(256) void xposeK_k(const float* __restrict__ Kt,
                                                float* __restrict__ Kdt) {
    __shared__ float tile[32][33];
    int l0 = blockIdx.x * 32, d0 = blockIdx.y * 32, bh = blockIdx.z;
    int col = threadIdx.x & 31, rw = threadIdx.x >> 5;   // 8 rows per pass
#pragma unroll
    for (int r = 0; r < 4; ++r) {
        int l = l0 + rw + r * 8;
        if (l < L_) tile[rw + r * 8][col] = Kt[((size_t)bh * L_ + l) * 64 + d0 + col];
    }
    __syncthreads();
#pragma unroll
    for (int r = 0; r < 4; ++r) {
        int d = rw + r * 8;
        int l = l0 + col;
        if (l < L_) Kdt[((size_t)bh * 64 + d0 + d) * L_ + l] = tile[col][d];
    }
}

// ======================================================================
// probscore v2: thread-per-l, u split 2-way over blockIdx.y, acc in regs.
// Writes partial (max, sum) -> Mp:  [uh][gl] max, [2+uh][gl] sum
// ======================================================================
__global__ __launch_bounds__(256) void probscore2_k(const float* __restrict__ Q,
                                                    const float* __restrict__ Kt,
                                                    const int* __restrict__ idxs,
                                                    float* __restrict__ Mp) {
    int gl = blockIdx.x * 256 + threadIdx.x;
    if (gl >= GL_) return;
    int uh = blockIdx.y;
    int bh = gl / L_, l = gl - bh * L_;

    int idxr[20];
#pragma unroll
    for (int u = 0; u < 20; ++u) idxr[u] = idxs[l * U_ + uh * 20 + u];

    const float4* Q4 = (const float4*)Q;
    const float4* Kb4 = (const float4*)Kt + (size_t)bh * L_ * 16;

    float acc[20];
#pragma unroll
    for (int u = 0; u < 20; ++u) acc[u] = 0.f;

#pragma unroll
    for (int dc = 0; dc < 4; ++dc) {
        float4 q0 = Q4[(size_t)gl * 16 + dc * 4 + 0];
        float4 q1 = Q4[(size_t)gl * 16 + dc * 4 + 1];
        float4 q2 = Q4[(size_t)gl * 16 + dc * 4 + 2];
        float4 q3 = Q4[(size_t)gl * 16 + dc * 4 + 3];
#pragma unroll
        for (int u = 0; u < 20; ++u) {
            const float4* kr = Kb4 + (size_t)idxr[u] * 16 + dc * 4;
            float4 a = kr[0], b = kr[1], c = kr[2], d = kr[3];
            float t = acc[u];
            t = fmaf(q0.x, a.x, t); t = fmaf(q0.y, a.y, t);
            t = fmaf(q0.z, a.z, t); t = fmaf(q0.w, a.w, t);
            t = fmaf(q1.x, b.x, t); t = fmaf(q1.y, b.y, t);
            t = fmaf(q1.z, b.z, t); t = fmaf(q1.w, b.w, t);
            t = fmaf(q2.x, c.x, t); t = fmaf(q2.y, c.y, t);
            t = fmaf(q2.z, c.z, t); t = fmaf(q2.w, c.w, t);
            t = fmaf(q3.x, d.x, t); t = fmaf(q3.y, d.y, t);
            t = fmaf(q3.z, d.z, t); t = fmaf(q3.w, d.w, t);
            acc[u] = t;
        }
    }
    float mx = -1e30f, sm = 0.f;
#pragma unroll
    for (int u = 0; u < 20; ++u) { mx = fmaxf(mx, acc[u]); sm += acc[u]; }
    Mp[(size_t)uh * GL_ + gl] = mx;
    Mp[(size_t)(2 + uh) * GL_ + gl] = sm;
}

// ======================================================================
// top-U per (b,h): single wave, shuffle argmax, combines probscore partials.
// JAX tie-break: equal value -> lower index.
// ======================================================================
__global__ __launch_bounds__(64) void topk_k(const float* __restrict__ Mp,
                                             int* __restrict__ Mtop) {
    __shared__ float sv[L_];
    int bh = blockIdx.x, lane = threadIdx.x;
    for (int i = lane; i < L_; i += 64) {
        int gl = bh * L_ + i;
        float mx = fmaxf(Mp[gl], Mp[(size_t)GL_ + gl]);
        float sm = Mp[(size_t)2 * GL_ + gl] + Mp[(size_t)3 * GL_ + gl];
        sv[i] = mx - sm * (1.0f / (float)L_);
    }
    __syncthreads();
    for (int it = 0; it < U_; ++it) {
        float bv = -1e30f; int bi = 1 << 30;
        for (int i = lane; i < L_; i += 64) {
            float v = sv[i];
            if (v > bv || (v == bv && i < bi)) { bv = v; bi = i; }
        }
#pragma unroll
        for (int o = 32; o >= 1; o >>= 1) {
            float v2 = __shfl_xor(bv, o);
            int   i2 = __shfl_xor(bi, o);
            if (v2 > bv || (v2 == bv && i2 < bi)) { bv = v2; bi = i2; }
        }
        if (lane == 0) { Mtop[bh * U_ + it] = bi; sv[bi] = -1e30f; }
        __syncthreads();
    }
}

// ======================================================================
// Vmean + ctx fill (unchanged)
// ======================================================================
__global__ __launch_bounds__(256) void vmean_k(const float* __restrict__ V,
                                               float* __restrict__ Vm) {
    __shared__ float red[256];
    int bh = blockIdx.x;
    int d = threadIdx.x & 63, part = threadIdx.x >> 6;
    const float* Vb = V + (size_t)bh * L_ * 64;
    float s = 0.f;
    for (int l = part; l < L_; l += 4) s += Vb[l * 64 + d];
    red[threadIdx.x] = s;
    __syncthreads();
    if (part == 0) {
        s = red[d] + red[64 + d] + red[128 + d] + red[192 + d];
        Vm[bh * 64 + d] = s / (float)L_;
    }
}

__global__ __launch_bounds__(256) void fill_ctx_k(const float* __restrict__ Vm,
                                                  float* __restrict__ ctxp) {
    int idx = blockIdx.x * 256 + threadIdx.x;
    if (idx >= B_ * L_ * 32) return;
    int c4 = idx & 31;
    int bl = idx >> 5;
    int b = bl / L_;
    int h = c4 >> 4, d4 = (c4 & 15) * 4;
    float4 v = *(const float4*)&Vm[(b * 2 + h) * 64 + d4];
    *(float4*)&ctxp[(size_t)idx * 4] = v;
}

// ======================================================================
// attn v2: block per (b,h,u). Scores via transposed K (coalesced float4,
// no shuffles), LDS-tree softmax, coalesced PV.
// ======================================================================
__global__ __launch_bounds__(256) void attn2_k(const float* __restrict__ Q,
                                               const float* __restrict__ Kdt,
                                               const float* __restrict__ V,
                                               const int* __restrict__ Mtop,
                                               float* __restrict__ ctxp) {
    __shared__ float4 s4buf[L4_];
    __shared__ float qs[64];
    __shared__ float red[256];
    __shared__ float bcast[2];
    float* s = (float*)s4buf;

    int tid = threadIdx.x;
    int bhu = blockIdx.x;
    int u = bhu % U_, bh = bhu / U_;
    int b = bh >> 1, h = bh & 1;
    int qi = Mtop[bh * U_ + u];

    if (tid < 16) ((float4*)qs)[tid] = ((const float4*)Q)[((size_t)bh * L_ + qi) * 16 + tid];
    __syncthreads();

    // ---- scores: thread per float4-of-l ----
    const float4* K4 = (const float4*)Kdt + (size_t)bh * 64 * L4_;
    float mx = -1e30f;
    for (int s4i = tid; s4i < L4_; s4i += 256) {
        float4 acc = {0.f, 0.f, 0.f, 0.f};
#pragma unroll 8
        for (int d = 0; d < 64; ++d) {
            float4 k4 = K4[(size_t)d * L4_ + s4i];
            float qd = qs[d];
            acc.x = fmaf(qd, k4.x, acc.x);
            acc.y = fmaf(qd, k4.y, acc.y);
            acc.z = fmaf(qd, k4.z, acc.z);
            acc.w = fmaf(qd, k4.w, acc.w);
        }
        acc.x *= 0.125f; acc.y *= 0.125f; acc.z *= 0.125f; acc.w *= 0.125f;
        s4buf[s4i] = acc;
        mx = fmaxf(mx, fmaxf(fmaxf(acc.x, acc.y), fmaxf(acc.z, acc.w)));
    }
    red[tid] = mx;
    __syncthreads();
    if (tid < 64) {
        float m4 = fmaxf(fmaxf(red[tid], red[tid + 64]), fmaxf(red[tid + 128], red[tid + 192]));
#pragma unroll
        for (int o = 32; o >= 1; o >>= 1) m4 = fmaxf(m4, __shfl_xor(m4, o));
        if (tid == 0) bcast[0] = m4;
    }
    __syncthreads();
    float bmx = bcast[0];

    // ---- exp + sum ----
    float ps = 0.f;
    for (int l = tid; l < L_; l += 256) {
        float e = __expf(s[l] - bmx);
        s[l] = e;
        ps += e;
    }
    red[tid] = ps;
    __syncthreads();
    if (tid < 64) {
        float s4s = red[tid] + red[tid + 64] + red[tid + 128] + red[tid + 192];
#pragma unroll
        for (int o = 32; o >= 1; o >>= 1) s4s += __shfl_xor(s4s, o);
        if (tid == 0) bcast[1] = s4s;
    }
    __syncthreads();
    float inv = 1.0f / bcast[1];

    // ---- PV: wave w handles l = w mod 4, lane = d ----
    int w = tid >> 6, lane = tid & 63;
    const float* Vb = V + (size_t)bh * L_ * 64;
    float acc = 0.f;
    for (int l = w; l < L_; l += 4) acc = fmaf(s[l], Vb[(size_t)l * 64 + lane], acc);
    red[tid] = acc;
    __syncthreads();
    if (w == 0) {
        float r = red[lane] + red[64 + lane] + red[128 + lane] + red[192 + lane];
        ctxp[((size_t)b * L_ + qi) * 128 + h * 64 + lane] = r * inv;
    }
}

// ======================================================================
// launch
// ======================================================================
extern "C" void kernel_launch(void* const* d_in, const int* in_sizes, int n_in,
                              void* d_out, int out_size, void* d_ws, size_t ws_size,
                              hipStream_t stream) {
    const float* x   = (const float*)d_in[0];
    const float* c1w = (const float*)d_in[1];
    const float* c1b = (const float*)d_in[2];
    const float* c2w = (const float*)d_in[3];
    const float* c2b = (const float*)d_in[4];
    const float* wq  = (const float*)d_in[5];
    const float* bq  = (const float*)d_in[6];
    const float* wk  = (const float*)d_in[7];
    const float* bk  = (const float*)d_in[8];
    const float* wv  = (const float*)d_in[9];
    const float* bv  = (const float*)d_in[10];
    const float* wo  = (const float*)d_in[11];
    const float* bo  = (const float*)d_in[12];
    const int* isamp = (const int*)d_in[13];
    float* out = (float*)d_out;

    float* ws   = (float*)d_ws;
    float* xp   = ws;                    // 524288  (also reused as Mp after conv1)
    float* w1m  = xp   + 524288;         // 32768
    float* w2m  = w1m  + 32768;          // 262144
    float* h1p  = w2m  + 262144;         // 3622912 (reused as Kdt after conv2)
    float* seq  = h1p  + 3622912;        // 3088384
    float* Q    = seq  + 3088384;        // 3088384
    float* Kt   = Q    + 3088384;        // 3088384
    float* V    = Kt   + 3088384;        // 3088384
    float* Vm   = V    + 3088384;        // 2048
    float* ctxp = Vm   + 2048;           // 3088384
    int*   Mtop = (int*)(ctxp + 3088384);// 1280 ints
    float* Kdt  = h1p;                   // alias: h1p dead after conv2
    float* Mp   = xp;                    // alias: xp dead after conv1 (4*GL_ floats)

    xpose_x<<<2048, 256, 0, stream>>>(x, xp);
    prep_w1<<<128, 256, 0, stream>>>(c1w, w1m);
    prep_w2<<<1024, 256, 0, stream>>>(c2w, w2m);

    gemm_k<1, 0, true, 16, 64, 32, 61, 29>
        <<<dim3(443, 2), 256, 0, stream>>>(xp, w1m, c1b, h1p, M1_, 256);
    gemm_k<1, 0, true, 128, 61, 29, 58, 26>
        <<<dim3(377, 2), 256, 0, stream>>>(h1p, w2m, c2b, seq, M2_, 2048);

    gemm_k<0, 1, false, 1, 1, 1, 1, 1>
        <<<dim3(377, 2), 256, 0, stream>>>(seq, wq, bq, Q, M2_, 128);
    gemm_k<0, 1, false, 1, 1, 1, 1, 1>
        <<<dim3(377, 2), 256, 0, stream>>>(seq, wk, bk, Kt, M2_, 128);
    gemm_k<0, 1, false, 1, 1, 1, 1, 1>
        <<<dim3(377, 2), 256, 0, stream>>>(seq, wv, bv, V, M2_, 128);

    xposeK_k<<<dim3(48, 2, 32), 256, 0, stream>>>(Kt, Kdt);
    probscore2_k<<<dim3(189, 2), 256, 0, stream>>>(Q, Kt, isamp, Mp);
    topk_k<<<32, 64, 0, stream>>>(Mp, Mtop);
    vmean_k<<<32, 256, 0, stream>>>(V, Vm);
    fill_ctx_k<<<3016, 256, 0, stream>>>(Vm, ctxp);
    attn2_k<<<1280, 256, 0, stream>>>(Q, Kdt, V, Mtop, ctxp);

    gemm_k<0, 0, false, 1, 1, 1, 1, 1>
        <<<dim3(377, 2), 256, 0, stream>>>(ctxp, wo, bo, out, M2_, 128);
}

// Round 3
// 778.412 us; speedup vs baseline: 1.1950x; 1.1817x over previous
//
#include <hip/hip_runtime.h>
#include <hip/hip_bf16.h>

// ---- problem constants ----
#define B_     16
#define NFEAT  16
#define TLEN   64
#define SCL    32
#define HID_   128
#define FS_    4
#define NH_    2
#define DH_    64
#define H1_    61
#define W1_    29
#define H2_    58
#define W2_    26
#define L_     1508     // 58*26
#define L4_    377      // L/4
#define U_     40       // 5*ceil(ln(1508))
#define M1_    28304    // B*H1*W1
#define M2_    24128    // B*L
#define GL_    48256    // B*NH*L

// ======================================================================
// small prep kernels
// ======================================================================

__global__ __launch_bounds__(256) void xpose_x(const float* __restrict__ x,
                                               float* __restrict__ xp) {
    int idx = blockIdx.x * 256 + threadIdx.x;
    if (idx >= B_ * NFEAT * TLEN * SCL) return;
    int xx = idx & 31; int t = idx >> 5;
    int y  = t & 63;   t >>= 6;
    int ic = t & 15;   int b = t >> 4;
    xp[(((b * TLEN + y) * SCL + xx) * NFEAT) + ic] = x[idx];
}

__global__ __launch_bounds__(256) void prep_w1(const float* __restrict__ w,
                                               float* __restrict__ wm) {
    int idx = blockIdx.x * 256 + threadIdx.x;
    if (idx >= 256 * 128) return;
    int co = idx & 127; int k = idx >> 7;
    int ic = k & 15; int s = k >> 4; int fy = s >> 2, fx = s & 3;
    wm[idx] = w[((co * NFEAT + ic) * FS_ + fy) * FS_ + fx];
}

__global__ __launch_bounds__(256) void prep_w2(const float* __restrict__ w,
                                               float* __restrict__ wm) {
    int idx = blockIdx.x * 256 + threadIdx.x;
    if (idx >= 2048 * 128) return;
    int co = idx & 127; int k = idx >> 7;
    int ic = k & 127; int s = k >> 7; int fy = s >> 2, fx = s & 3;
    wm[idx] = w[((co * HID_ + ic) * FS_ + fy) * FS_ + fx];
}

// ======================================================================
// tiled fp32 GEMM (unchanged)
// ======================================================================
template <int ASRC, int OSTORE, bool RELU, int CIN, int HIN, int WIN, int HOUT, int WOUT>
__global__ __launch_bounds__(256) void gemm_k(const float* __restrict__ A,
                                              const float* __restrict__ Bm,
                                              const float* __restrict__ bias,
                                              float* __restrict__ C,
                                              int Mrows, int K) {
    __shared__ float As[32][68];
    __shared__ float Bs[32][68];
    const int tid = threadIdx.x;
    const int tx = tid & 15, ty = tid >> 4;
    const int m0 = blockIdx.x * 64;
    const int n0 = blockIdx.y * 64;

    float acc[4][4] = {};

    for (int k0 = 0; k0 < K; k0 += 32) {
#pragma unroll
        for (int i = 0; i < 2; ++i) {
            int s = tid + i * 256;
            int kk = s >> 4, n4 = s & 15;
            float4 v = *(const float4*)&Bm[(size_t)(k0 + kk) * 128 + n0 + n4 * 4];
            *(float4*)&Bs[kk][n4 * 4] = v;
        }
#pragma unroll
        for (int i = 0; i < 2; ++i) {
            int s = tid + i * 256;
            int row = s >> 3, kq = s & 7;
            int m = m0 + row;
            if (m >= Mrows) m = Mrows - 1;
            int k = k0 + kq * 4;
            const float* src;
            if constexpr (ASRC == 0) {
                src = &A[(size_t)m * K + k];
            } else {
                int bb = m / (HOUT * WOUT), r = m % (HOUT * WOUT);
                int y = r / WOUT, xx = r % WOUT;
                int slice = k / CIN, ic = k - slice * CIN;
                int fy = slice / FS_, fx = slice % FS_;
                src = &A[(size_t)(((bb * HIN + y + fy) * WIN) + (xx + fx)) * CIN + ic];
            }
            float4 v = *(const float4*)src;
            As[kq * 4 + 0][row] = v.x;
            As[kq * 4 + 1][row] = v.y;
            As[kq * 4 + 2][row] = v.z;
            As[kq * 4 + 3][row] = v.w;
        }
        __syncthreads();
#pragma unroll
        for (int k = 0; k < 32; ++k) {
            float4 av = *(const float4*)&As[k][ty * 4];
            float4 bv = *(const float4*)&Bs[k][tx * 4];
            float a_[4] = {av.x, av.y, av.z, av.w};
            float b_[4] = {bv.x, bv.y, bv.z, bv.w};
#pragma unroll
            for (int i = 0; i < 4; ++i)
#pragma unroll
                for (int j = 0; j < 4; ++j)
                    acc[i][j] = fmaf(a_[i], b_[j], acc[i][j]);
        }
        __syncthreads();
    }

    float bb4[4];
#pragma unroll
    for (int j = 0; j < 4; ++j) bb4[j] = bias[n0 + tx * 4 + j];
#pragma unroll
    for (int i = 0; i < 4; ++i) {
        int m = m0 + ty * 4 + i;
        if (m >= Mrows) continue;
        float4 v;
        float* vp = (float*)&v;
#pragma unroll
        for (int j = 0; j < 4; ++j) {
            float t = acc[i][j] + bb4[j];
            if (RELU) t = fmaxf(t, 0.f);
            vp[j] = t;
        }
        if constexpr (OSTORE == 0) {
            *(float4*)&C[(size_t)m * 128 + n0 + tx * 4] = v;
        } else {
            int b = m / L_, l = m - b * L_;
            int h = n0 >> 6;
            *(float4*)&C[(((size_t)(b * NH_ + h) * L_ + l) << 6) + tx * 4] = v;
        }
    }
}

// ======================================================================
// K transpose: Kt[bh][l][d] -> Kdt[bh][d][l]
// ======================================================================
__global__ __launch_bounds__(256) void xposeK_k(const float* __restrict__ Kt,
                                                float* __restrict__ Kdt) {
    __shared__ float tile[32][33];
    int l0 = blockIdx.x * 32, d0 = blockIdx.y * 32, bh = blockIdx.z;
    int col = threadIdx.x & 31, rw = threadIdx.x >> 5;
#pragma unroll
    for (int r = 0; r < 4; ++r) {
        int l = l0 + rw + r * 8;
        if (l < L_) tile[rw + r * 8][col] = Kt[((size_t)bh * L_ + l) * 64 + d0 + col];
    }
    __syncthreads();
#pragma unroll
    for (int r = 0; r < 4; ++r) {
        int d = rw + r * 8;
        int l = l0 + col;
        if (l < L_) Kdt[((size_t)bh * 64 + d0 + d) * L_ + l] = tile[col][d];
    }
}

// ======================================================================
// probscore v3: XCD-local (grid.x = bh -> XCD = bh%8, K[bh] L2-resident),
// 8-way u-split per l for occupancy, whole-row contiguous float4 gathers.
// Thread = (bh, l, uh): 5 u's. Partials -> Mp[uh][gl] max, Mp[8+uh][gl] sum.
// grid (32, 48), block 256: l = chunk*32 + tid/8, uh = tid%8
// ======================================================================
__global__ __launch_bounds__(256) void probscore3_k(const float* __restrict__ Q,
                                                    const float* __restrict__ Kt,
                                                    const int* __restrict__ idxs,
                                                    float* __restrict__ Mp) {
    int bh = blockIdx.x;
    int l  = blockIdx.y * 32 + (threadIdx.x >> 3);
    int uh = threadIdx.x & 7;
    if (l >= L_) return;
    int gl = bh * L_ + l;

    int idxr[5];
#pragma unroll
    for (int j = 0; j < 5; ++j) idxr[j] = idxs[l * U_ + uh * 5 + j];

    const float4* Q4  = (const float4*)Q + (size_t)gl * 16;
    const float4* Kb4 = (const float4*)Kt + (size_t)bh * L_ * 16;

    float acc[5];
#pragma unroll
    for (int j = 0; j < 5; ++j) acc[j] = 0.f;

#pragma unroll
    for (int dc = 0; dc < 4; ++dc) {
        float4 q0 = Q4[dc * 4 + 0];
        float4 q1 = Q4[dc * 4 + 1];
        float4 q2 = Q4[dc * 4 + 2];
        float4 q3 = Q4[dc * 4 + 3];
#pragma unroll
        for (int j = 0; j < 5; ++j) {
            const float4* kr = Kb4 + (size_t)idxr[j] * 16 + dc * 4;
            float4 a = kr[0], b = kr[1], c = kr[2], d = kr[3];
            float t = acc[j];
            t = fmaf(q0.x, a.x, t); t = fmaf(q0.y, a.y, t);
            t = fmaf(q0.z, a.z, t); t = fmaf(q0.w, a.w, t);
            t = fmaf(q1.x, b.x, t); t = fmaf(q1.y, b.y, t);
            t = fmaf(q1.z, b.z, t); t = fmaf(q1.w, b.w, t);
            t = fmaf(q2.x, c.x, t); t = fmaf(q2.y, c.y, t);
            t = fmaf(q2.z, c.z, t); t = fmaf(q2.w, c.w, t);
            t = fmaf(q3.x, d.x, t); t = fmaf(q3.y, d.y, t);
            t = fmaf(q3.z, d.z, t); t = fmaf(q3.w, d.w, t);
            acc[j] = t;
        }
    }
    float mx = -1e30f, sm = 0.f;
#pragma unroll
    for (int j = 0; j < 5; ++j) { mx = fmaxf(mx, acc[j]); sm += acc[j]; }
    Mp[(size_t)uh * GL_ + gl] = mx;
    Mp[(size_t)(8 + uh) * GL_ + gl] = sm;
}

// ======================================================================
// top-U per (b,h): single wave, shuffle argmax, combines 8 partials.
// ======================================================================
__global__ __launch_bounds__(64) void topk_k(const float* __restrict__ Mp,
                                             int* __restrict__ Mtop) {
    __shared__ float sv[L_];
    int bh = blockIdx.x, lane = threadIdx.x;
    for (int i = lane; i < L_; i += 64) {
        int gl = bh * L_ + i;
        float mx = -1e30f, sm = 0.f;
#pragma unroll
        for (int uh = 0; uh < 8; ++uh) {
            mx = fmaxf(mx, Mp[(size_t)uh * GL_ + gl]);
            sm += Mp[(size_t)(8 + uh) * GL_ + gl];
        }
        sv[i] = mx - sm * (1.0f / (float)L_);
    }
    __syncthreads();
    for (int it = 0; it < U_; ++it) {
        float bv = -1e30f; int bi = 1 << 30;
        for (int i = lane; i < L_; i += 64) {
            float v = sv[i];
            if (v > bv || (v == bv && i < bi)) { bv = v; bi = i; }
        }
#pragma unroll
        for (int o = 32; o >= 1; o >>= 1) {
            float v2 = __shfl_xor(bv, o);
            int   i2 = __shfl_xor(bi, o);
            if (v2 > bv || (v2 == bv && i2 < bi)) { bv = v2; bi = i2; }
        }
        if (lane == 0) { Mtop[bh * U_ + it] = bi; sv[bi] = -1e30f; }
        __syncthreads();
    }
}

// ======================================================================
// Vmean + ctx fill
// ======================================================================
__global__ __launch_bounds__(256) void vmean_k(const float* __restrict__ V,
                                               float* __restrict__ Vm) {
    __shared__ float red[256];
    int bh = blockIdx.x;
    int d = threadIdx.x & 63, part = threadIdx.x >> 6;
    const float* Vb = V + (size_t)bh * L_ * 64;
    float s = 0.f;
    for (int l = part; l < L_; l += 4) s += Vb[l * 64 + d];
    red[threadIdx.x] = s;
    __syncthreads();
    if (part == 0) {
        s = red[d] + red[64 + d] + red[128 + d] + red[192 + d];
        Vm[bh * 64 + d] = s / (float)L_;
    }
}

__global__ __launch_bounds__(256) void fill_ctx_k(const float* __restrict__ Vm,
                                                  float* __restrict__ ctxp) {
    int idx = blockIdx.x * 256 + threadIdx.x;
    if (idx >= B_ * L_ * 32) return;
    int c4 = idx & 31;
    int bl = idx >> 5;
    int b = bl / L_;
    int h = c4 >> 4, d4 = (c4 & 15) * 4;
    float4 v = *(const float4*)&Vm[(b * 2 + h) * 64 + d4];
    *(float4*)&ctxp[(size_t)idx * 4] = v;
}

// ======================================================================
// attn v2 (unchanged from R2)
// ======================================================================
__global__ __launch_bounds__(256) void attn2_k(const float* __restrict__ Q,
                                               const float* __restrict__ Kdt,
                                               const float* __restrict__ V,
                                               const int* __restrict__ Mtop,
                                               float* __restrict__ ctxp) {
    __shared__ float4 s4buf[L4_];
    __shared__ float qs[64];
    __shared__ float red[256];
    __shared__ float bcast[2];
    float* s = (float*)s4buf;

    int tid = threadIdx.x;
    int bhu = blockIdx.x;
    int u = bhu % U_, bh = bhu / U_;
    int b = bh >> 1, h = bh & 1;
    int qi = Mtop[bh * U_ + u];

    if (tid < 16) ((float4*)qs)[tid] = ((const float4*)Q)[((size_t)bh * L_ + qi) * 16 + tid];
    __syncthreads();

    const float4* K4 = (const float4*)Kdt + (size_t)bh * 64 * L4_;
    float mx = -1e30f;
    for (int s4i = tid; s4i < L4_; s4i += 256) {
        float4 acc = {0.f, 0.f, 0.f, 0.f};
#pragma unroll 8
        for (int d = 0; d < 64; ++d) {
            float4 k4 = K4[(size_t)d * L4_ + s4i];
            float qd = qs[d];
            acc.x = fmaf(qd, k4.x, acc.x);
            acc.y = fmaf(qd, k4.y, acc.y);
            acc.z = fmaf(qd, k4.z, acc.z);
            acc.w = fmaf(qd, k4.w, acc.w);
        }
        acc.x *= 0.125f; acc.y *= 0.125f; acc.z *= 0.125f; acc.w *= 0.125f;
        s4buf[s4i] = acc;
        mx = fmaxf(mx, fmaxf(fmaxf(acc.x, acc.y), fmaxf(acc.z, acc.w)));
    }
    red[tid] = mx;
    __syncthreads();
    if (tid < 64) {
        float m4 = fmaxf(fmaxf(red[tid], red[tid + 64]), fmaxf(red[tid + 128], red[tid + 192]));
#pragma unroll
        for (int o = 32; o >= 1; o >>= 1) m4 = fmaxf(m4, __shfl_xor(m4, o));
        if (tid == 0) bcast[0] = m4;
    }
    __syncthreads();
    float bmx = bcast[0];

    float ps = 0.f;
    for (int l = tid; l < L_; l += 256) {
        float e = __expf(s[l] - bmx);
        s[l] = e;
        ps += e;
    }
    red[tid] = ps;
    __syncthreads();
    if (tid < 64) {
        float s4s = red[tid] + red[tid + 64] + red[tid + 128] + red[tid + 192];
#pragma unroll
        for (int o = 32; o >= 1; o >>= 1) s4s += __shfl_xor(s4s, o);
        if (tid == 0) bcast[1] = s4s;
    }
    __syncthreads();
    float inv = 1.0f / bcast[1];

    int w = tid >> 6, lane = tid & 63;
    const float* Vb = V + (size_t)bh * L_ * 64;
    float acc = 0.f;
    for (int l = w; l < L_; l += 4) acc = fmaf(s[l], Vb[(size_t)l * 64 + lane], acc);
    red[tid] = acc;
    __syncthreads();
    if (w == 0) {
        float r = red[lane] + red[64 + lane] + red[128 + lane] + red[192 + lane];
        ctxp[((size_t)b * L_ + qi) * 128 + h * 64 + lane] = r * inv;
    }
}

// ======================================================================
// launch
// ======================================================================
extern "C" void kernel_launch(void* const* d_in, const int* in_sizes, int n_in,
                              void* d_out, int out_size, void* d_ws, size_t ws_size,
                              hipStream_t stream) {
    const float* x   = (const float*)d_in[0];
    const float* c1w = (const float*)d_in[1];
    const float* c1b = (const float*)d_in[2];
    const float* c2w = (const float*)d_in[3];
    const float* c2b = (const float*)d_in[4];
    const float* wq  = (const float*)d_in[5];
    const float* bq  = (const float*)d_in[6];
    const float* wk  = (const float*)d_in[7];
    const float* bk  = (const float*)d_in[8];
    const float* wv  = (const float*)d_in[9];
    const float* bv  = (const float*)d_in[10];
    const float* wo  = (const float*)d_in[11];
    const float* bo  = (const float*)d_in[12];
    const int* isamp = (const int*)d_in[13];
    float* out = (float*)d_out;

    float* ws   = (float*)d_ws;
    float* xp   = ws;                    // 524288
    float* w1m  = xp   + 524288;         // 32768
    float* w2m  = w1m  + 32768;          // 262144
    float* h1p  = w2m  + 262144;         // 3622912 (reused as Kdt after conv2)
    float* seq  = h1p  + 3622912;        // 3088384
    float* Q    = seq  + 3088384;        // 3088384
    float* Kt   = Q    + 3088384;        // 3088384
    float* V    = Kt   + 3088384;        // 3088384
    float* Vm   = V    + 3088384;        // 2048
    float* ctxp = Vm   + 2048;           // 3088384
    int*   Mtop = (int*)(ctxp + 3088384);// 1280 ints
    float* Kdt  = h1p;                   // alias: h1p dead after conv2
    float* Mp   = ws;                    // alias: xp+w1m+w2m (819200 floats) dead
                                         // after convs; need 16*GL_=772096. OK.

    xpose_x<<<2048, 256, 0, stream>>>(x, xp);
    prep_w1<<<128, 256, 0, stream>>>(c1w, w1m);
    prep_w2<<<1024, 256, 0, stream>>>(c2w, w2m);

    gemm_k<1, 0, true, 16, 64, 32, 61, 29>
        <<<dim3(443, 2), 256, 0, stream>>>(xp, w1m, c1b, h1p, M1_, 256);
    gemm_k<1, 0, true, 128, 61, 29, 58, 26>
        <<<dim3(377, 2), 256, 0, stream>>>(h1p, w2m, c2b, seq, M2_, 2048);

    gemm_k<0, 1, false, 1, 1, 1, 1, 1>
        <<<dim3(377, 2), 256, 0, stream>>>(seq, wq, bq, Q, M2_, 128);
    gemm_k<0, 1, false, 1, 1, 1, 1, 1>
        <<<dim3(377, 2), 256, 0, stream>>>(seq, wk, bk, Kt, M2_, 128);
    gemm_k<0, 1, false, 1, 1, 1, 1, 1>
        <<<dim3(377, 2), 256, 0, stream>>>(seq, wv, bv, V, M2_, 128);

    xposeK_k<<<dim3(48, 2, 32), 256, 0, stream>>>(Kt, Kdt);
    // grid.x = bh so XCD = (bh + 32*chunk) % 8 = bh % 8 -> K[bh] L2-local
    probscore3_k<<<dim3(32, 48), 256, 0, stream>>>(Q, Kt, isamp, Mp);
    topk_k<<<32, 64, 0, stream>>>(Mp, Mtop);
    vmean_k<<<32, 256, 0, stream>>>(V, Vm);
    fill_ctx_k<<<3016, 256, 0, stream>>>(Vm, ctxp);
    attn2_k<<<1280, 256, 0, stream>>>(Q, Kdt, V, Mtop, ctxp);

    gemm_k<0, 0, false, 1, 1, 1, 1, 1>
        <<<dim3(377, 2), 256, 0, stream>>>(ctxp, wo, bo, out, M2_, 128);
}

// Round 4
// 676.757 us; speedup vs baseline: 1.3744x; 1.1502x over previous
//
#include <hip/hip_runtime.h>
#include <hip/hip_bf16.h>

// ---- problem constants ----
#define B_     16
#define NFEAT  16
#define TLEN   64
#define SCL    32
#define HID_   128
#define FS_    4
#define NH_    2
#define DH_    64
#define H1_    61
#define W1_    29
#define H2_    58
#define W2_    26
#define L_     1508     // 58*26
#define L4_    377      // L/4
#define U_     40       // 5*ceil(ln(1508))
#define M1_    28304    // B*H1*W1
#define M2_    24128    // B*L
#define GL_    48256    // B*NH*L

typedef unsigned short u16;
typedef __attribute__((ext_vector_type(8))) short short8v;
typedef __attribute__((ext_vector_type(16))) float f32x16;

// ---- bf16 split helpers (RNE) ----
__device__ inline unsigned bf16rne_u(float f) {
    unsigned u = __float_as_uint(f);
    return (u + 0x7FFFu + ((u >> 16) & 1u)) >> 16;
}
__device__ inline void split2(float f, u16& h, u16& l) {
    unsigned r = bf16rne_u(f);
    h = (u16)r;
    float hf = __uint_as_float((r & 0xFFFFu) << 16);
    unsigned r2 = bf16rne_u(f - hf);
    l = (u16)r2;
}

// ======================================================================
// prep kernels: split inputs/weights to bf16 hi/lo (weights transposed)
// ======================================================================

// x (B,16,64,32) -> xp_hi/lo (B,64,32,16) channel-last split
__global__ __launch_bounds__(256) void xpose_x_split(const float* __restrict__ x,
                                                     u16* __restrict__ xh,
                                                     u16* __restrict__ xl) {
    int idx = blockIdx.x * 256 + threadIdx.x;
    if (idx >= B_ * NFEAT * TLEN * SCL) return;
    int xx = idx & 31; int t = idx >> 5;
    int y  = t & 63;   t >>= 6;
    int ic = t & 15;   int b = t >> 4;
    u16 h, l;
    split2(x[idx], h, l);
    size_t dst = (((size_t)(b * TLEN + y) * SCL + xx) * NFEAT) + ic;
    xh[dst] = h; xl[dst] = l;
}

// conv w (co,CIN,4,4) -> wt_hi/lo [co][K], k = (fy*4+fx)*CIN + ic
template <int CIN>
__global__ __launch_bounds__(256) void prep_cw(const float* __restrict__ w,
                                               u16* __restrict__ wh,
                                               u16* __restrict__ wl) {
    const int K = CIN * 16;
    int idx = blockIdx.x * 256 + threadIdx.x;
    if (idx >= 128 * K) return;
    int co = idx / K, k = idx - co * K;
    int ic = k % CIN, s = k / CIN;
    int fy = s >> 2, fx = s & 3;
    u16 h, l;
    split2(w[((co * CIN + ic) * FS_ + fy) * FS_ + fx], h, l);
    wh[idx] = h; wl[idx] = l;
}

// mat w (128,128) [k][n] -> wt_hi/lo [n][k]
__global__ __launch_bounds__(256) void prep_mw(const float* __restrict__ w,
                                               u16* __restrict__ wh,
                                               u16* __restrict__ wl) {
    int idx = blockIdx.x * 256 + threadIdx.x;
    if (idx >= 128 * 128) return;
    int n = idx >> 7, k = idx & 127;
    u16 h, l;
    split2(w[k * 128 + n], h, l);
    wh[idx] = h; wl[idx] = l;
}

// ======================================================================
// split-bf16 MFMA GEMM: C[M x 128] = op(A)[M x K] @ B[K x 128] + bias
// BM=128, BN=128, BK=64; 256 thr = 4 waves (2x2); wave tile 64x64 =
// 2x2 frags of mfma_f32_32x32x16_bf16. 3 MFMAs per frag pair (hi/lo split).
// ASRC: 0 = row-major, 1 = implicit im2col (channel-last input)
// ABF:  1 = A pre-split u16 hi/lo arrays, 0 = A fp32 (convert in staging)
// OSTORE: 0 = fp32 C[m*128+n]; 1 = QKV scatter; 2 = u16 hi/lo pair out
// LDS rows swizzled: 16B-chunk c stored at c ^ (row&7).
// ======================================================================
template <int ASRC, int ABF, int OSTORE, bool RELU,
          int CIN, int HIN, int WIN, int HOUT, int WOUT>
__global__ __launch_bounds__(256, 2) void mgemm_k(const void* __restrict__ Ahv,
                                                  const void* __restrict__ Alv,
                                                  const u16* __restrict__ Bhg,
                                                  const u16* __restrict__ Blg,
                                                  const float* __restrict__ bias,
                                                  void* __restrict__ C0v,
                                                  void* __restrict__ C1v,
                                                  int Mrows, int K) {
    __shared__ u16 Ah_s[128 * 64];
    __shared__ u16 Al_s[128 * 64];
    __shared__ u16 Bh_s[128 * 64];
    __shared__ u16 Bl_s[128 * 64];

    const int tid = threadIdx.x;
    const int m0 = blockIdx.x * 128;
    const int wv = tid >> 6, lane = tid & 63;
    const int wm = wv >> 1, wn = wv & 1;
    const int lr = lane & 31;          // frag row (A) / col (B/D)
    const int kh = lane >> 5;          // k-half selector

    f32x16 acc[2][2];
#pragma unroll
    for (int i = 0; i < 2; ++i)
#pragma unroll
        for (int j = 0; j < 2; ++j)
#pragma unroll
            for (int r = 0; r < 16; ++r) acc[i][j][r] = 0.f;

    for (int k0 = 0; k0 < K; k0 += 64) {
        // ---- stage A: 128 rows x 64 k, 1024 groups of 8 ----
#pragma unroll
        for (int g = 0; g < 4; ++g) {
            int gi = tid + g * 256;
            int row = gi >> 3, c = gi & 7;
            int m = m0 + row;
            if (m >= Mrows) m = Mrows - 1;
            int k = k0 + c * 8;
            size_t src;
            if constexpr (ASRC == 0) {
                src = (size_t)m * K + k;
            } else {
                int bb = m / (HOUT * WOUT), r = m % (HOUT * WOUT);
                int y = r / WOUT, xx = r % WOUT;
                int slice = k / CIN, ic = k - slice * CIN;
                int fy = slice >> 2, fx = slice & 3;
                src = ((size_t)((bb * HIN + y + fy) * WIN) + (xx + fx)) * CIN + ic;
            }
            int dst = row * 64 + ((c ^ (row & 7)) * 8);
            if constexpr (ABF == 1) {
                *(short8v*)&Ah_s[dst] = *(const short8v*)((const u16*)Ahv + src);
                *(short8v*)&Al_s[dst] = *(const short8v*)((const u16*)Alv + src);
            } else {
                const float* Af = (const float*)Ahv;
                float vv[8];
                *(float4*)&vv[0] = *(const float4*)&Af[src];
                *(float4*)&vv[4] = *(const float4*)&Af[src + 4];
                short8v hv, lv;
#pragma unroll
                for (int j = 0; j < 8; ++j) {
                    u16 h, l;
                    split2(vv[j], h, l);
                    hv[j] = (short)h; lv[j] = (short)l;
                }
                *(short8v*)&Ah_s[dst] = hv;
                *(short8v*)&Al_s[dst] = lv;
            }
        }
        // ---- stage B: 128 n x 64 k from [n][K] global ----
#pragma unroll
        for (int i = 0; i < 4; ++i) {
            int s = tid + i * 256;
            int nn = s >> 3, c = s & 7;
            size_t src = (size_t)nn * K + k0 + c * 8;
            int dst = nn * 64 + ((c ^ (nn & 7)) * 8);
            *(short8v*)&Bh_s[dst] = *(const short8v*)&Bhg[src];
            *(short8v*)&Bl_s[dst] = *(const short8v*)&Blg[src];
        }
        __syncthreads();
        // ---- compute: 4 k-sub-steps of 16 ----
#pragma unroll
        for (int ks = 0; ks < 4; ++ks) {
            const int ch = ks * 2 + kh;
            short8v ah[2], al[2], bh[2], bl[2];
#pragma unroll
            for (int mf = 0; mf < 2; ++mf) {
                int row = wm * 64 + mf * 32 + lr;
                int idx = row * 64 + ((ch ^ (row & 7)) * 8);
                ah[mf] = *(const short8v*)&Ah_s[idx];
                al[mf] = *(const short8v*)&Al_s[idx];
            }
#pragma unroll
            for (int nf = 0; nf < 2; ++nf) {
                int rn = wn * 64 + nf * 32 + lr;
                int idx = rn * 64 + ((ch ^ (rn & 7)) * 8);
                bh[nf] = *(const short8v*)&Bh_s[idx];
                bl[nf] = *(const short8v*)&Bl_s[idx];
            }
#pragma unroll
            for (int mf = 0; mf < 2; ++mf)
#pragma unroll
                for (int nf = 0; nf < 2; ++nf) {
                    acc[mf][nf] = __builtin_amdgcn_mfma_f32_32x32x16_bf16(
                        ah[mf], bh[nf], acc[mf][nf], 0, 0, 0);
                    acc[mf][nf] = __builtin_amdgcn_mfma_f32_32x32x16_bf16(
                        ah[mf], bl[nf], acc[mf][nf], 0, 0, 0);
                    acc[mf][nf] = __builtin_amdgcn_mfma_f32_32x32x16_bf16(
                        al[mf], bh[nf], acc[mf][nf], 0, 0, 0);
                }
        }
        __syncthreads();
    }

    // ---- epilogue. C/D frag: col = lane&31, row = (r&3)+8*(r>>2)+4*(lane>>5) ----
#pragma unroll
    for (int mf = 0; mf < 2; ++mf)
#pragma unroll
        for (int nf = 0; nf < 2; ++nf) {
            int n = wn * 64 + nf * 32 + lr;
            float bv = bias[n];
#pragma unroll
            for (int r = 0; r < 16; ++r) {
                int row = (r & 3) + 8 * (r >> 2) + 4 * kh;
                int m = m0 + wm * 64 + mf * 32 + row;
                if (m >= Mrows) continue;
                float t = acc[mf][nf][r] + bv;
                if (RELU) t = fmaxf(t, 0.f);
                if constexpr (OSTORE == 0) {
                    ((float*)C0v)[(size_t)m * 128 + n] = t;
                } else if constexpr (OSTORE == 1) {
                    int b = m / L_, l = m - b * L_;
                    int h = n >> 6, d = n & 63;
                    ((float*)C0v)[(((size_t)(b * NH_ + h) * L_ + l) << 6) + d] = t;
                } else {
                    u16 h, l;
                    split2(t, h, l);
                    ((u16*)C0v)[(size_t)m * 128 + n] = h;
                    ((u16*)C1v)[(size_t)m * 128 + n] = l;
                }
            }
        }
}

// ======================================================================
// K transpose: Kt[bh][l][d] -> Kdt[bh][d][l]
// ======================================================================
__global__ __launch_bounds__(256) void xposeK_k(const float* __restrict__ Kt,
                                                float* __restrict__ Kdt) {
    __shared__ float tile[32][33];
    int l0 = blockIdx.x * 32, d0 = blockIdx.y * 32, bh = blockIdx.z;
    int col = threadIdx.x & 31, rw = threadIdx.x >> 5;
#pragma unroll
    for (int r = 0; r < 4; ++r) {
        int l = l0 + rw + r * 8;
        if (l < L_) tile[rw + r * 8][col] = Kt[((size_t)bh * L_ + l) * 64 + d0 + col];
    }
    __syncthreads();
#pragma unroll
    for (int r = 0; r < 4; ++r) {
        int d = rw + r * 8;
        int l = l0 + col;
        if (l < L_) Kdt[((size_t)bh * 64 + d0 + d) * L_ + l] = tile[col][d];
    }
}

// ======================================================================
// probscore v3 (unchanged from R3)
// ======================================================================
__global__ __launch_bounds__(256) void probscore3_k(const float* __restrict__ Q,
                                                    const float* __restrict__ Kt,
                                                    const int* __restrict__ idxs,
                                                    float* __restrict__ Mp) {
    int bh = blockIdx.x;
    int l  = blockIdx.y * 32 + (threadIdx.x >> 3);
    int uh = threadIdx.x & 7;
    if (l >= L_) return;
    int gl = bh * L_ + l;

    int idxr[5];
#pragma unroll
    for (int j = 0; j < 5; ++j) idxr[j] = idxs[l * U_ + uh * 5 + j];

    const float4* Q4  = (const float4*)Q + (size_t)gl * 16;
    const float4* Kb4 = (const float4*)Kt + (size_t)bh * L_ * 16;

    float acc[5];
#pragma unroll
    for (int j = 0; j < 5; ++j) acc[j] = 0.f;

#pragma unroll
    for (int dc = 0; dc < 4; ++dc) {
        float4 q0 = Q4[dc * 4 + 0];
        float4 q1 = Q4[dc * 4 + 1];
        float4 q2 = Q4[dc * 4 + 2];
        float4 q3 = Q4[dc * 4 + 3];
#pragma unroll
        for (int j = 0; j < 5; ++j) {
            const float4* kr = Kb4 + (size_t)idxr[j] * 16 + dc * 4;
            float4 a = kr[0], b = kr[1], c = kr[2], d = kr[3];
            float t = acc[j];
            t = fmaf(q0.x, a.x, t); t = fmaf(q0.y, a.y, t);
            t = fmaf(q0.z, a.z, t); t = fmaf(q0.w, a.w, t);
            t = fmaf(q1.x, b.x, t); t = fmaf(q1.y, b.y, t);
            t = fmaf(q1.z, b.z, t); t = fmaf(q1.w, b.w, t);
            t = fmaf(q2.x, c.x, t); t = fmaf(q2.y, c.y, t);
            t = fmaf(q2.z, c.z, t); t = fmaf(q2.w, c.w, t);
            t = fmaf(q3.x, d.x, t); t = fmaf(q3.y, d.y, t);
            t = fmaf(q3.z, d.z, t); t = fmaf(q3.w, d.w, t);
            acc[j] = t;
        }
    }
    float mx = -1e30f, sm = 0.f;
#pragma unroll
    for (int j = 0; j < 5; ++j) { mx = fmaxf(mx, acc[j]); sm += acc[j]; }
    Mp[(size_t)uh * GL_ + gl] = mx;
    Mp[(size_t)(8 + uh) * GL_ + gl] = sm;
}

// ======================================================================
// top-U per (b,h) (unchanged from R3)
// ======================================================================
__global__ __launch_bounds__(64) void topk_k(const float* __restrict__ Mp,
                                             int* __restrict__ Mtop) {
    __shared__ float sv[L_];
    int bh = blockIdx.x, lane = threadIdx.x;
    for (int i = lane; i < L_; i += 64) {
        int gl = bh * L_ + i;
        float mx = -1e30f, sm = 0.f;
#pragma unroll
        for (int uh = 0; uh < 8; ++uh) {
            mx = fmaxf(mx, Mp[(size_t)uh * GL_ + gl]);
            sm += Mp[(size_t)(8 + uh) * GL_ + gl];
        }
        sv[i] = mx - sm * (1.0f / (float)L_);
    }
    __syncthreads();
    for (int it = 0; it < U_; ++it) {
        float bv = -1e30f; int bi = 1 << 30;
        for (int i = lane; i < L_; i += 64) {
            float v = sv[i];
            if (v > bv || (v == bv && i < bi)) { bv = v; bi = i; }
        }
#pragma unroll
        for (int o = 32; o >= 1; o >>= 1) {
            float v2 = __shfl_xor(bv, o);
            int   i2 = __shfl_xor(bi, o);
            if (v2 > bv || (v2 == bv && i2 < bi)) { bv = v2; bi = i2; }
        }
        if (lane == 0) { Mtop[bh * U_ + it] = bi; sv[bi] = -1e30f; }
        __syncthreads();
    }
}

// ======================================================================
// Vmean + ctx fill (unchanged)
// ======================================================================
__global__ __launch_bounds__(256) void vmean_k(const float* __restrict__ V,
                                               float* __restrict__ Vm) {
    __shared__ float red[256];
    int bh = blockIdx.x;
    int d = threadIdx.x & 63, part = threadIdx.x >> 6;
    const float* Vb = V + (size_t)bh * L_ * 64;
    float s = 0.f;
    for (int l = part; l < L_; l += 4) s += Vb[l * 64 + d];
    red[threadIdx.x] = s;
    __syncthreads();
    if (part == 0) {
        s = red[d] + red[64 + d] + red[128 + d] + red[192 + d];
        Vm[bh * 64 + d] = s / (float)L_;
    }
}

__global__ __launch_bounds__(256) void fill_ctx_k(const float* __restrict__ Vm,
                                                  float* __restrict__ ctxp) {
    int idx = blockIdx.x * 256 + threadIdx.x;
    if (idx >= B_ * L_ * 32) return;
    int c4 = idx & 31;
    int bl = idx >> 5;
    int b = bl / L_;
    int h = c4 >> 4, d4 = (c4 & 15) * 4;
    float4 v = *(const float4*)&Vm[(b * 2 + h) * 64 + d4];
    *(float4*)&ctxp[(size_t)idx * 4] = v;
}

// ======================================================================
// attn v2 (unchanged from R3)
// ======================================================================
__global__ __launch_bounds__(256) void attn2_k(const float* __restrict__ Q,
                                               const float* __restrict__ Kdt,
                                               const float* __restrict__ V,
                                               const int* __restrict__ Mtop,
                                               float* __restrict__ ctxp) {
    __shared__ float4 s4buf[L4_];
    __shared__ float qs[64];
    __shared__ float red[256];
    __shared__ float bcast[2];
    float* s = (float*)s4buf;

    int tid = threadIdx.x;
    int bhu = blockIdx.x;
    int u = bhu % U_, bh = bhu / U_;
    int b = bh >> 1, h = bh & 1;
    int qi = Mtop[bh * U_ + u];

    if (tid < 16) ((float4*)qs)[tid] = ((const float4*)Q)[((size_t)bh * L_ + qi) * 16 + tid];
    __syncthreads();

    const float4* K4 = (const float4*)Kdt + (size_t)bh * 64 * L4_;
    float mx = -1e30f;
    for (int s4i = tid; s4i < L4_; s4i += 256) {
        float4 acc = {0.f, 0.f, 0.f, 0.f};
#pragma unroll 8
        for (int d = 0; d < 64; ++d) {
            float4 k4 = K4[(size_t)d * L4_ + s4i];
            float qd = qs[d];
            acc.x = fmaf(qd, k4.x, acc.x);
            acc.y = fmaf(qd, k4.y, acc.y);
            acc.z = fmaf(qd, k4.z, acc.z);
            acc.w = fmaf(qd, k4.w, acc.w);
        }
        acc.x *= 0.125f; acc.y *= 0.125f; acc.z *= 0.125f; acc.w *= 0.125f;
        s4buf[s4i] = acc;
        mx = fmaxf(mx, fmaxf(fmaxf(acc.x, acc.y), fmaxf(acc.z, acc.w)));
    }
    red[tid] = mx;
    __syncthreads();
    if (tid < 64) {
        float m4 = fmaxf(fmaxf(red[tid], red[tid + 64]), fmaxf(red[tid + 128], red[tid + 192]));
#pragma unroll
        for (int o = 32; o >= 1; o >>= 1) m4 = fmaxf(m4, __shfl_xor(m4, o));
        if (tid == 0) bcast[0] = m4;
    }
    __syncthreads();
    float bmx = bcast[0];

    float ps = 0.f;
    for (int l = tid; l < L_; l += 256) {
        float e = __expf(s[l] - bmx);
        s[l] = e;
        ps += e;
    }
    red[tid] = ps;
    __syncthreads();
    if (tid < 64) {
        float s4s = red[tid] + red[tid + 64] + red[tid + 128] + red[tid + 192];
#pragma unroll
        for (int o = 32; o >= 1; o >>= 1) s4s += __shfl_xor(s4s, o);
        if (tid == 0) bcast[1] = s4s;
    }
    __syncthreads();
    float inv = 1.0f / bcast[1];

    int w = tid >> 6, lane = tid & 63;
    const float* Vb = V + (size_t)bh * L_ * 64;
    float acc = 0.f;
    for (int l = w; l < L_; l += 4) acc = fmaf(s[l], Vb[(size_t)l * 64 + lane], acc);
    red[tid] = acc;
    __syncthreads();
    if (w == 0) {
        float r = red[lane] + red[64 + lane] + red[128 + lane] + red[192 + lane];
        ctxp[((size_t)b * L_ + qi) * 128 + h * 64 + lane] = r * inv;
    }
}

// ======================================================================
// launch
// ======================================================================
extern "C" void kernel_launch(void* const* d_in, const int* in_sizes, int n_in,
                              void* d_out, int out_size, void* d_ws, size_t ws_size,
                              hipStream_t stream) {
    const float* x   = (const float*)d_in[0];
    const float* c1w = (const float*)d_in[1];
    const float* c1b = (const float*)d_in[2];
    const float* c2w = (const float*)d_in[3];
    const float* c2b = (const float*)d_in[4];
    const float* wq  = (const float*)d_in[5];
    const float* bq  = (const float*)d_in[6];
    const float* wk  = (const float*)d_in[7];
    const float* bk  = (const float*)d_in[8];
    const float* wv  = (const float*)d_in[9];
    const float* bv  = (const float*)d_in[10];
    const float* wo  = (const float*)d_in[11];
    const float* bo  = (const float*)d_in[12];
    const int* isamp = (const int*)d_in[13];
    float* out = (float*)d_out;

    // ---- workspace layout (256B-aligned byte cursor) ----
    char* cur = (char*)d_ws;
    auto alloc = [&](size_t bytes) {
        char* p = cur;
        cur += (bytes + 255) & ~(size_t)255;
        return p;
    };
    u16* xp_h  = (u16*)alloc(524288 * 2);
    u16* xp_l  = (u16*)alloc(524288 * 2);
    u16* wt1h  = (u16*)alloc(32768 * 2);
    u16* wt1l  = (u16*)alloc(32768 * 2);
    u16* wt2h  = (u16*)alloc(262144 * 2);
    u16* wt2l  = (u16*)alloc(262144 * 2);
    u16* wtqh  = (u16*)alloc(16384 * 2);
    u16* wtql  = (u16*)alloc(16384 * 2);
    u16* wtkh  = (u16*)alloc(16384 * 2);
    u16* wtkl  = (u16*)alloc(16384 * 2);
    u16* wtvh  = (u16*)alloc(16384 * 2);
    u16* wtvl  = (u16*)alloc(16384 * 2);
    u16* wtoh  = (u16*)alloc(16384 * 2);
    u16* wtol  = (u16*)alloc(16384 * 2);
    u16* h1_h  = (u16*)alloc(3622912 * 2);   // (B,61,29,128) split
    u16* h1_l  = (u16*)alloc(3622912 * 2);
    u16* seq_h = (u16*)alloc(3088384 * 2);   // (B*L,128) split
    u16* seq_l = (u16*)alloc(3088384 * 2);
    float* Q    = (float*)alloc(3088384 * 4);
    float* Kt   = (float*)alloc(3088384 * 4);
    float* V    = (float*)alloc(3088384 * 4);
    float* Vm   = (float*)alloc(2048 * 4);
    float* ctxp = (float*)alloc(3088384 * 4);
    int*   Mtop = (int*)alloc(1280 * 4);
    float* Kdt  = (float*)h1_h;              // alias: h1 dead after conv2 (14.5MB >= 12.4MB)
    float* Mp   = (float*)seq_h;             // alias: seq dead after projections (12.4MB >= 3.1MB)

    // ---- prep: split/transpose ----
    xpose_x_split<<<2048, 256, 0, stream>>>(x, xp_h, xp_l);
    prep_cw<16><<<128, 256, 0, stream>>>(c1w, wt1h, wt1l);
    prep_cw<128><<<1024, 256, 0, stream>>>(c2w, wt2h, wt2l);
    prep_mw<<<64, 256, 0, stream>>>(wq, wtqh, wtql);
    prep_mw<<<64, 256, 0, stream>>>(wk, wtkh, wtkl);
    prep_mw<<<64, 256, 0, stream>>>(wv, wtvh, wtvl);
    prep_mw<<<64, 256, 0, stream>>>(wo, wtoh, wtol);

    // ---- conv1: im2col MFMA, K=256, ReLU -> h1 split ----
    mgemm_k<1, 1, 2, true, 16, 64, 32, 61, 29>
        <<<222, 256, 0, stream>>>(xp_h, xp_l, wt1h, wt1l, c1b, h1_h, h1_l, M1_, 256);
    // ---- conv2: im2col MFMA, K=2048, ReLU -> seq split ----
    mgemm_k<1, 1, 2, true, 128, 61, 29, 58, 26>
        <<<189, 256, 0, stream>>>(h1_h, h1_l, wt2h, wt2l, c2b, seq_h, seq_l, M2_, 2048);

    // ---- Q/K/V projections (fp32 out, (b,h,l,d) scatter) ----
    mgemm_k<0, 1, 1, false, 1, 1, 1, 1, 1>
        <<<189, 256, 0, stream>>>(seq_h, seq_l, wtqh, wtql, bq, Q, nullptr, M2_, 128);
    mgemm_k<0, 1, 1, false, 1, 1, 1, 1, 1>
        <<<189, 256, 0, stream>>>(seq_h, seq_l, wtkh, wtkl, bk, Kt, nullptr, M2_, 128);
    mgemm_k<0, 1, 1, false, 1, 1, 1, 1, 1>
        <<<189, 256, 0, stream>>>(seq_h, seq_l, wtvh, wtvl, bv, V, nullptr, M2_, 128);

    // ---- attention path (fp32, unchanged) ----
    xposeK_k<<<dim3(48, 2, 32), 256, 0, stream>>>(Kt, Kdt);
    probscore3_k<<<dim3(32, 48), 256, 0, stream>>>(Q, Kt, isamp, Mp);
    topk_k<<<32, 64, 0, stream>>>(Mp, Mtop);
    vmean_k<<<32, 256, 0, stream>>>(V, Vm);
    fill_ctx_k<<<3016, 256, 0, stream>>>(Vm, ctxp);
    attn2_k<<<1280, 256, 0, stream>>>(Q, Kdt, V, Mtop, ctxp);

    // ---- out = ctxp @ wo + bo (fp32 A, converted in staging) ----
    mgemm_k<0, 0, 0, false, 1, 1, 1, 1, 1>
        <<<189, 256, 0, stream>>>(ctxp, nullptr, wtoh, wtol, bo, out, nullptr, M2_, 128);
}

// Round 6
// 612.510 us; speedup vs baseline: 1.5186x; 1.1049x over previous
//
#include <hip/hip_runtime.h>
#include <hip/hip_bf16.h>

// ---- problem constants ----
#define B_     16
#define NFEAT  16
#define TLEN   64
#define SCL    32
#define HID_   128
#define FS_    4
#define NH_    2
#define DH_    64
#define H1_    61
#define W1_    29
#define H2_    58
#define W2_    26
#define L_     1508     // 58*26
#define L4_    377      // L/4
#define U_     40       // 5*ceil(ln(1508))
#define M1_    28304    // B*H1*W1
#define M2_    24128    // B*L
#define GL_    48256    // B*NH*L

typedef unsigned short u16;
typedef __attribute__((ext_vector_type(8))) short short8v;
typedef __attribute__((ext_vector_type(16))) float f32x16;

// ---- bf16 split helpers (RNE) ----
__device__ inline unsigned bf16rne_u(float f) {
    unsigned u = __float_as_uint(f);
    return (u + 0x7FFFu + ((u >> 16) & 1u)) >> 16;
}
__device__ inline void split2(float f, u16& h, u16& l) {
    unsigned r = bf16rne_u(f);
    h = (u16)r;
    float hf = __uint_as_float((r & 0xFFFFu) << 16);
    unsigned r2 = bf16rne_u(f - hf);
    l = (u16)r2;
}

// ======================================================================
// prep kernels: split inputs/weights to bf16 hi/lo (weights transposed)
// ======================================================================

__global__ __launch_bounds__(256) void xpose_x_split(const float* __restrict__ x,
                                                     u16* __restrict__ xh,
                                                     u16* __restrict__ xl) {
    int idx = blockIdx.x * 256 + threadIdx.x;
    if (idx >= B_ * NFEAT * TLEN * SCL) return;
    int xx = idx & 31; int t = idx >> 5;
    int y  = t & 63;   t >>= 6;
    int ic = t & 15;   int b = t >> 4;
    u16 h, l;
    split2(x[idx], h, l);
    size_t dst = (((size_t)(b * TLEN + y) * SCL + xx) * NFEAT) + ic;
    xh[dst] = h; xl[dst] = l;
}

template <int CIN>
__global__ __launch_bounds__(256) void prep_cw(const float* __restrict__ w,
                                               u16* __restrict__ wh,
                                               u16* __restrict__ wl) {
    const int K = CIN * 16;
    int idx = blockIdx.x * 256 + threadIdx.x;
    if (idx >= 128 * K) return;
    int co = idx / K, k = idx - co * K;
    int ic = k % CIN, s = k / CIN;
    int fy = s >> 2, fx = s & 3;
    u16 h, l;
    split2(w[((co * CIN + ic) * FS_ + fy) * FS_ + fx], h, l);
    wh[idx] = h; wl[idx] = l;
}

__global__ __launch_bounds__(256) void prep_mw(const float* __restrict__ w,
                                               u16* __restrict__ wh,
                                               u16* __restrict__ wl) {
    int idx = blockIdx.x * 256 + threadIdx.x;
    if (idx >= 128 * 128) return;
    int n = idx >> 7, k = idx & 127;
    u16 h, l;
    split2(w[k * 128 + n], h, l);
    wh[idx] = h; wl[idx] = l;
}

// ======================================================================
// split-bf16 MFMA GEMM (unchanged from R4)
// ======================================================================
template <int ASRC, int ABF, int OSTORE, bool RELU,
          int CIN, int HIN, int WIN, int HOUT, int WOUT>
__global__ __launch_bounds__(256, 2) void mgemm_k(const void* __restrict__ Ahv,
                                                  const void* __restrict__ Alv,
                                                  const u16* __restrict__ Bhg,
                                                  const u16* __restrict__ Blg,
                                                  const float* __restrict__ bias,
                                                  void* __restrict__ C0v,
                                                  void* __restrict__ C1v,
                                                  int Mrows, int K) {
    __shared__ u16 Ah_s[128 * 64];
    __shared__ u16 Al_s[128 * 64];
    __shared__ u16 Bh_s[128 * 64];
    __shared__ u16 Bl_s[128 * 64];

    const int tid = threadIdx.x;
    const int m0 = blockIdx.x * 128;
    const int wv = tid >> 6, lane = tid & 63;
    const int wm = wv >> 1, wn = wv & 1;
    const int lr = lane & 31;
    const int kh = lane >> 5;

    f32x16 acc[2][2];
#pragma unroll
    for (int i = 0; i < 2; ++i)
#pragma unroll
        for (int j = 0; j < 2; ++j)
#pragma unroll
            for (int r = 0; r < 16; ++r) acc[i][j][r] = 0.f;

    for (int k0 = 0; k0 < K; k0 += 64) {
#pragma unroll
        for (int g = 0; g < 4; ++g) {
            int gi = tid + g * 256;
            int row = gi >> 3, c = gi & 7;
            int m = m0 + row;
            if (m >= Mrows) m = Mrows - 1;
            int k = k0 + c * 8;
            size_t src;
            if constexpr (ASRC == 0) {
                src = (size_t)m * K + k;
            } else {
                int bb = m / (HOUT * WOUT), r = m % (HOUT * WOUT);
                int y = r / WOUT, xx = r % WOUT;
                int slice = k / CIN, ic = k - slice * CIN;
                int fy = slice >> 2, fx = slice & 3;
                src = ((size_t)((bb * HIN + y + fy) * WIN) + (xx + fx)) * CIN + ic;
            }
            int dst = row * 64 + ((c ^ (row & 7)) * 8);
            if constexpr (ABF == 1) {
                *(short8v*)&Ah_s[dst] = *(const short8v*)((const u16*)Ahv + src);
                *(short8v*)&Al_s[dst] = *(const short8v*)((const u16*)Alv + src);
            } else {
                const float* Af = (const float*)Ahv;
                float vv[8];
                *(float4*)&vv[0] = *(const float4*)&Af[src];
                *(float4*)&vv[4] = *(const float4*)&Af[src + 4];
                short8v hv, lv;
#pragma unroll
                for (int j = 0; j < 8; ++j) {
                    u16 h, l;
                    split2(vv[j], h, l);
                    hv[j] = (short)h; lv[j] = (short)l;
                }
                *(short8v*)&Ah_s[dst] = hv;
                *(short8v*)&Al_s[dst] = lv;
            }
        }
#pragma unroll
        for (int i = 0; i < 4; ++i) {
            int s = tid + i * 256;
            int nn = s >> 3, c = s & 7;
            size_t src = (size_t)nn * K + k0 + c * 8;
            int dst = nn * 64 + ((c ^ (nn & 7)) * 8);
            *(short8v*)&Bh_s[dst] = *(const short8v*)&Bhg[src];
            *(short8v*)&Bl_s[dst] = *(const short8v*)&Blg[src];
        }
        __syncthreads();
#pragma unroll
        for (int ks = 0; ks < 4; ++ks) {
            const int ch = ks * 2 + kh;
            short8v ah[2], al[2], bh[2], bl[2];
#pragma unroll
            for (int mf = 0; mf < 2; ++mf) {
                int row = wm * 64 + mf * 32 + lr;
                int idx = row * 64 + ((ch ^ (row & 7)) * 8);
                ah[mf] = *(const short8v*)&Ah_s[idx];
                al[mf] = *(const short8v*)&Al_s[idx];
            }
#pragma unroll
            for (int nf = 0; nf < 2; ++nf) {
                int rn = wn * 64 + nf * 32 + lr;
                int idx = rn * 64 + ((ch ^ (rn & 7)) * 8);
                bh[nf] = *(const short8v*)&Bh_s[idx];
                bl[nf] = *(const short8v*)&Bl_s[idx];
            }
#pragma unroll
            for (int mf = 0; mf < 2; ++mf)
#pragma unroll
                for (int nf = 0; nf < 2; ++nf) {
                    acc[mf][nf] = __builtin_amdgcn_mfma_f32_32x32x16_bf16(
                        ah[mf], bh[nf], acc[mf][nf], 0, 0, 0);
                    acc[mf][nf] = __builtin_amdgcn_mfma_f32_32x32x16_bf16(
                        ah[mf], bl[nf], acc[mf][nf], 0, 0, 0);
                    acc[mf][nf] = __builtin_amdgcn_mfma_f32_32x32x16_bf16(
                        al[mf], bh[nf], acc[mf][nf], 0, 0, 0);
                }
        }
        __syncthreads();
    }

#pragma unroll
    for (int mf = 0; mf < 2; ++mf)
#pragma unroll
        for (int nf = 0; nf < 2; ++nf) {
            int n = wn * 64 + nf * 32 + lr;
            float bv = bias[n];
#pragma unroll
            for (int r = 0; r < 16; ++r) {
                int row = (r & 3) + 8 * (r >> 2) + 4 * kh;
                int m = m0 + wm * 64 + mf * 32 + row;
                if (m >= Mrows) continue;
                float t = acc[mf][nf][r] + bv;
                if (RELU) t = fmaxf(t, 0.f);
                if constexpr (OSTORE == 0) {
                    ((float*)C0v)[(size_t)m * 128 + n] = t;
                } else if constexpr (OSTORE == 1) {
                    int b = m / L_, l = m - b * L_;
                    int h = n >> 6, d = n & 63;
                    ((float*)C0v)[(((size_t)(b * NH_ + h) * L_ + l) << 6) + d] = t;
                } else {
                    u16 h, l;
                    split2(t, h, l);
                    ((u16*)C0v)[(size_t)m * 128 + n] = h;
                    ((u16*)C1v)[(size_t)m * 128 + n] = l;
                }
            }
        }
}

// ======================================================================
// K transpose: Kt[bh][l][d] -> Kdt[bh][d][l]
// ======================================================================
__global__ __launch_bounds__(256) void xposeK_k(const float* __restrict__ Kt,
                                                float* __restrict__ Kdt) {
    __shared__ float tile[32][33];
    int l0 = blockIdx.x * 32, d0 = blockIdx.y * 32, bh = blockIdx.z;
    int col = threadIdx.x & 31, rw = threadIdx.x >> 5;
#pragma unroll
    for (int r = 0; r < 4; ++r) {
        int l = l0 + rw + r * 8;
        if (l < L_) tile[rw + r * 8][col] = Kt[((size_t)bh * L_ + l) * 64 + d0 + col];
    }
    __syncthreads();
#pragma unroll
    for (int r = 0; r < 4; ++r) {
        int d = rw + r * 8;
        int l = l0 + col;
        if (l < L_) Kdt[((size_t)bh * 64 + d0 + d) * L_ + l] = tile[col][d];
    }
}

// ======================================================================
// probscore v3 (unchanged)
// ======================================================================
__global__ __launch_bounds__(256) void probscore3_k(const float* __restrict__ Q,
                                                    const float* __restrict__ Kt,
                                                    const int* __restrict__ idxs,
                                                    float* __restrict__ Mp) {
    int bh = blockIdx.x;
    int l  = blockIdx.y * 32 + (threadIdx.x >> 3);
    int uh = threadIdx.x & 7;
    if (l >= L_) return;
    int gl = bh * L_ + l;

    int idxr[5];
#pragma unroll
    for (int j = 0; j < 5; ++j) idxr[j] = idxs[l * U_ + uh * 5 + j];

    const float4* Q4  = (const float4*)Q + (size_t)gl * 16;
    const float4* Kb4 = (const float4*)Kt + (size_t)bh * L_ * 16;

    float acc[5];
#pragma unroll
    for (int j = 0; j < 5; ++j) acc[j] = 0.f;

#pragma unroll
    for (int dc = 0; dc < 4; ++dc) {
        float4 q0 = Q4[dc * 4 + 0];
        float4 q1 = Q4[dc * 4 + 1];
        float4 q2 = Q4[dc * 4 + 2];
        float4 q3 = Q4[dc * 4 + 3];
#pragma unroll
        for (int j = 0; j < 5; ++j) {
            const float4* kr = Kb4 + (size_t)idxr[j] * 16 + dc * 4;
            float4 a = kr[0], b = kr[1], c = kr[2], d = kr[3];
            float t = acc[j];
            t = fmaf(q0.x, a.x, t); t = fmaf(q0.y, a.y, t);
            t = fmaf(q0.z, a.z, t); t = fmaf(q0.w, a.w, t);
            t = fmaf(q1.x, b.x, t); t = fmaf(q1.y, b.y, t);
            t = fmaf(q1.z, b.z, t); t = fmaf(q1.w, b.w, t);
            t = fmaf(q2.x, c.x, t); t = fmaf(q2.y, c.y, t);
            t = fmaf(q2.z, c.z, t); t = fmaf(q2.w, c.w, t);
            t = fmaf(q3.x, d.x, t); t = fmaf(q3.y, d.y, t);
            t = fmaf(q3.z, d.z, t); t = fmaf(q3.w, d.w, t);
            acc[j] = t;
        }
    }
    float mx = -1e30f, sm = 0.f;
#pragma unroll
    for (int j = 0; j < 5; ++j) { mx = fmaxf(mx, acc[j]); sm += acc[j]; }
    Mp[(size_t)uh * GL_ + gl] = mx;
    Mp[(size_t)(8 + uh) * GL_ + gl] = sm;
}

// ======================================================================
// top-U per (b,h) (unchanged)
// ======================================================================
__global__ __launch_bounds__(64) void topk_k(const float* __restrict__ Mp,
                                             int* __restrict__ Mtop) {
    __shared__ float sv[L_];
    int bh = blockIdx.x, lane = threadIdx.x;
    for (int i = lane; i < L_; i += 64) {
        int gl = bh * L_ + i;
        float mx = -1e30f, sm = 0.f;
#pragma unroll
        for (int uh = 0; uh < 8; ++uh) {
            mx = fmaxf(mx, Mp[(size_t)uh * GL_ + gl]);
            sm += Mp[(size_t)(8 + uh) * GL_ + gl];
        }
        sv[i] = mx - sm * (1.0f / (float)L_);
    }
    __syncthreads();
    for (int it = 0; it < U_; ++it) {
        float bv = -1e30f; int bi = 1 << 30;
        for (int i = lane; i < L_; i += 64) {
            float v = sv[i];
            if (v > bv || (v == bv && i < bi)) { bv = v; bi = i; }
        }
#pragma unroll
        for (int o = 32; o >= 1; o >>= 1) {
            float v2 = __shfl_xor(bv, o);
            int   i2 = __shfl_xor(bi, o);
            if (v2 > bv || (v2 == bv && i2 < bi)) { bv = v2; bi = i2; }
        }
        if (lane == 0) { Mtop[bh * U_ + it] = bi; sv[bi] = -1e30f; }
        __syncthreads();
    }
}

// ======================================================================
// Vmean + ctx fill (unchanged)
// ======================================================================
__global__ __launch_bounds__(256) void vmean_k(const float* __restrict__ V,
                                               float* __restrict__ Vm) {
    __shared__ float red[256];
    int bh = blockIdx.x;
    int d = threadIdx.x & 63, part = threadIdx.x >> 6;
    const float* Vb = V + (size_t)bh * L_ * 64;
    float s = 0.f;
    for (int l = part; l < L_; l += 4) s += Vb[l * 64 + d];
    red[threadIdx.x] = s;
    __syncthreads();
    if (part == 0) {
        s = red[d] + red[64 + d] + red[128 + d] + red[192 + d];
        Vm[bh * 64 + d] = s / (float)L_;
    }
}

__global__ __launch_bounds__(256) void fill_ctx_k(const float* __restrict__ Vm,
                                                  float* __restrict__ ctxp) {
    int idx = blockIdx.x * 256 + threadIdx.x;
    if (idx >= B_ * L_ * 32) return;
    int c4 = idx & 31;
    int bl = idx >> 5;
    int b = bl / L_;
    int h = c4 >> 4, d4 = (c4 & 15) * 4;
    float4 v = *(const float4*)&Vm[(b * 2 + h) * 64 + d4];
    *(float4*)&ctxp[(size_t)idx * 4] = v;
}

// ======================================================================
// attn v3: identical to v2 except the block->(bh,u) decode is XCD-local:
// bh = bhu & 31  =>  XCD (= flat%8) = bh%8, so each XCD's L2 serves only
// 4 bh (4 x 772KB = 3MB < 4MB) instead of all 32 (24.7MB thrash).
// ======================================================================
__global__ __launch_bounds__(256) void attn2_k(const float* __restrict__ Q,
                                               const float* __restrict__ Kdt,
                                               const float* __restrict__ V,
                                               const int* __restrict__ Mtop,
                                               float* __restrict__ ctxp) {
    __shared__ float4 s4buf[L4_];
    __shared__ float qs[64];
    __shared__ float red[256];
    __shared__ float bcast[2];
    float* s = (float*)s4buf;

    int tid = threadIdx.x;
    int bhu = blockIdx.x;
    int bh = bhu & 31, u = bhu >> 5;     // XCD-local: XCD = bh%8
    int b = bh >> 1, h = bh & 1;
    int qi = Mtop[bh * U_ + u];

    if (tid < 16) ((float4*)qs)[tid] = ((const float4*)Q)[((size_t)bh * L_ + qi) * 16 + tid];
    __syncthreads();

    const float4* K4 = (const float4*)Kdt + (size_t)bh * 64 * L4_;
    float mx = -1e30f;
    for (int s4i = tid; s4i < L4_; s4i += 256) {
        float4 acc = {0.f, 0.f, 0.f, 0.f};
#pragma unroll 8
        for (int d = 0; d < 64; ++d) {
            float4 k4 = K4[(size_t)d * L4_ + s4i];
            float qd = qs[d];
            acc.x = fmaf(qd, k4.x, acc.x);
            acc.y = fmaf(qd, k4.y, acc.y);
            acc.z = fmaf(qd, k4.z, acc.z);
            acc.w = fmaf(qd, k4.w, acc.w);
        }
        acc.x *= 0.125f; acc.y *= 0.125f; acc.z *= 0.125f; acc.w *= 0.125f;
        s4buf[s4i] = acc;
        mx = fmaxf(mx, fmaxf(fmaxf(acc.x, acc.y), fmaxf(acc.z, acc.w)));
    }
    red[tid] = mx;
    __syncthreads();
    if (tid < 64) {
        float m4 = fmaxf(fmaxf(red[tid], red[tid + 64]), fmaxf(red[tid + 128], red[tid + 192]));
#pragma unroll
        for (int o = 32; o >= 1; o >>= 1) m4 = fmaxf(m4, __shfl_xor(m4, o));
        if (tid == 0) bcast[0] = m4;
    }
    __syncthreads();
    float bmx = bcast[0];

    float ps = 0.f;
    for (int l = tid; l < L_; l += 256) {
        float e = __expf(s[l] - bmx);
        s[l] = e;
        ps += e;
    }
    red[tid] = ps;
    __syncthreads();
    if (tid < 64) {
        float s4s = red[tid] + red[tid + 64] + red[tid + 128] + red[tid + 192];
#pragma unroll
        for (int o = 32; o >= 1; o >>= 1) s4s += __shfl_xor(s4s, o);
        if (tid == 0) bcast[1] = s4s;
    }
    __syncthreads();
    float inv = 1.0f / bcast[1];

    int w = tid >> 6, lane = tid & 63;
    const float* Vb = V + (size_t)bh * L_ * 64;
    float acc = 0.f;
    for (int l = w; l < L_; l += 4) acc = fmaf(s[l], Vb[(size_t)l * 64 + lane], acc);
    red[tid] = acc;
    __syncthreads();
    if (w == 0) {
        float r = red[lane] + red[64 + lane] + red[128 + lane] + red[192 + lane];
        ctxp[((size_t)b * L_ + qi) * 128 + h * 64 + lane] = r * inv;
    }
}

// ======================================================================
// launch
// ======================================================================
extern "C" void kernel_launch(void* const* d_in, const int* in_sizes, int n_in,
                              void* d_out, int out_size, void* d_ws, size_t ws_size,
                              hipStream_t stream) {
    const float* x   = (const float*)d_in[0];
    const float* c1w = (const float*)d_in[1];
    const float* c1b = (const float*)d_in[2];
    const float* c2w = (const float*)d_in[3];
    const float* c2b = (const float*)d_in[4];
    const float* wq  = (const float*)d_in[5];
    const float* bq  = (const float*)d_in[6];
    const float* wk  = (const float*)d_in[7];
    const float* bk  = (const float*)d_in[8];
    const float* wv  = (const float*)d_in[9];
    const float* bv  = (const float*)d_in[10];
    const float* wo  = (const float*)d_in[11];
    const float* bo  = (const float*)d_in[12];
    const int* isamp = (const int*)d_in[13];
    float* out = (float*)d_out;

    char* cur = (char*)d_ws;
    auto alloc = [&](size_t bytes) {
        char* p = cur;
        cur += (bytes + 255) & ~(size_t)255;
        return p;
    };
    u16* xp_h  = (u16*)alloc(524288 * 2);
    u16* xp_l  = (u16*)alloc(524288 * 2);
    u16* wt1h  = (u16*)alloc(32768 * 2);
    u16* wt1l  = (u16*)alloc(32768 * 2);
    u16* wt2h  = (u16*)alloc(262144 * 2);
    u16* wt2l  = (u16*)alloc(262144 * 2);
    u16* wtqh  = (u16*)alloc(16384 * 2);
    u16* wtql  = (u16*)alloc(16384 * 2);
    u16* wtkh  = (u16*)alloc(16384 * 2);
    u16* wtkl  = (u16*)alloc(16384 * 2);
    u16* wtvh  = (u16*)alloc(16384 * 2);
    u16* wtvl  = (u16*)alloc(16384 * 2);
    u16* wtoh  = (u16*)alloc(16384 * 2);
    u16* wtol  = (u16*)alloc(16384 * 2);
    u16* h1_h  = (u16*)alloc(3622912 * 2);
    u16* h1_l  = (u16*)alloc(3622912 * 2);
    u16* seq_h = (u16*)alloc(3088384 * 2);
    u16* seq_l = (u16*)alloc(3088384 * 2);
    float* Q    = (float*)alloc(3088384 * 4);
    float* Kt   = (float*)alloc(3088384 * 4);
    float* V    = (float*)alloc(3088384 * 4);
    float* Vm   = (float*)alloc(2048 * 4);
    float* ctxp = (float*)alloc(3088384 * 4);
    int*   Mtop = (int*)alloc(1280 * 4);
    float* Kdt  = (float*)h1_h;
    float* Mp   = (float*)seq_h;

    xpose_x_split<<<2048, 256, 0, stream>>>(x, xp_h, xp_l);
    prep_cw<16><<<128, 256, 0, stream>>>(c1w, wt1h, wt1l);
    prep_cw<128><<<1024, 256, 0, stream>>>(c2w, wt2h, wt2l);
    prep_mw<<<64, 256, 0, stream>>>(wq, wtqh, wtql);
    prep_mw<<<64, 256, 0, stream>>>(wk, wtkh, wtkl);
    prep_mw<<<64, 256, 0, stream>>>(wv, wtvh, wtvl);
    prep_mw<<<64, 256, 0, stream>>>(wo, wtoh, wtol);

    mgemm_k<1, 1, 2, true, 16, 64, 32, 61, 29>
        <<<222, 256, 0, stream>>>(xp_h, xp_l, wt1h, wt1l, c1b, h1_h, h1_l, M1_, 256);
    mgemm_k<1, 1, 2, true, 128, 61, 29, 58, 26>
        <<<189, 256, 0, stream>>>(h1_h, h1_l, wt2h, wt2l, c2b, seq_h, seq_l, M2_, 2048);

    mgemm_k<0, 1, 1, false, 1, 1, 1, 1, 1>
        <<<189, 256, 0, stream>>>(seq_h, seq_l, wtqh, wtql, bq, Q, nullptr, M2_, 128);
    mgemm_k<0, 1, 1, false, 1, 1, 1, 1, 1>
        <<<189, 256, 0, stream>>>(seq_h, seq_l, wtkh, wtkl, bk, Kt, nullptr, M2_, 128);
    mgemm_k<0, 1, 1, false, 1, 1, 1, 1, 1>
        <<<189, 256, 0, stream>>>(seq_h, seq_l, wtvh, wtvl, bv, V, nullptr, M2_, 128);

    xposeK_k<<<dim3(48, 2, 32), 256, 0, stream>>>(Kt, Kdt);
    probscore3_k<<<dim3(32, 48), 256, 0, stream>>>(Q, Kt, isamp, Mp);
    topk_k<<<32, 64, 0, stream>>>(Mp, Mtop);
    vmean_k<<<32, 256, 0, stream>>>(V, Vm);
    fill_ctx_k<<<3016, 256, 0, stream>>>(Vm, ctxp);
    attn2_k<<<1280, 256, 0, stream>>>(Q, Kdt, V, Mtop, ctxp);

    mgemm_k<0, 0, 0, false, 1, 1, 1, 1, 1>
        <<<189, 256, 0, stream>>>(ctxp, nullptr, wtoh, wtol, bo, out, nullptr, M2_, 128);
}

// Round 10
// 517.527 us; speedup vs baseline: 1.7973x; 1.1835x over previous
//
#include <hip/hip_runtime.h>
#include <hip/hip_bf16.h>

// ---- problem constants ----
#define B_     16
#define NFEAT  16
#define TLEN   64
#define SCL    32
#define HID_   128
#define FS_    4
#define NH_    2
#define DH_    64
#define H1_    61
#define W1_    29
#define H2_    58
#define W2_    26
#define L_     1508     // 58*26
#define L4_    377      // L/4
#define U_     40       // 5*ceil(ln(1508))
#define M1_    28304    // B*H1*W1
#define M2_    24128    // B*L
#define GL_    48256    // B*NH*L

typedef unsigned short u16;
typedef unsigned long long u64;
typedef __attribute__((ext_vector_type(8))) short short8v;
typedef __attribute__((ext_vector_type(16))) float f32x16;

// ---- bf16 split helpers (RNE) ----
__device__ inline unsigned bf16rne_u(float f) {
    unsigned u = __float_as_uint(f);
    return (u + 0x7FFFu + ((u >> 16) & 1u)) >> 16;
}
__device__ inline void split2(float f, u16& h, u16& l) {
    unsigned r = bf16rne_u(f);
    h = (u16)r;
    float hf = __uint_as_float((r & 0xFFFFu) << 16);
    unsigned r2 = bf16rne_u(f - hf);
    l = (u16)r2;
}

// ======================================================================
// prep kernels: split inputs/weights to bf16 hi/lo (weights transposed)
// ======================================================================

__global__ __launch_bounds__(256) void xpose_x_split(const float* __restrict__ x,
                                                     u16* __restrict__ xh,
                                                     u16* __restrict__ xl) {
    int idx = blockIdx.x * 256 + threadIdx.x;
    if (idx >= B_ * NFEAT * TLEN * SCL) return;
    int xx = idx & 31; int t = idx >> 5;
    int y  = t & 63;   t >>= 6;
    int ic = t & 15;   int b = t >> 4;
    u16 h, l;
    split2(x[idx], h, l);
    size_t dst = (((size_t)(b * TLEN + y) * SCL + xx) * NFEAT) + ic;
    xh[dst] = h; xl[dst] = l;
}

template <int CIN>
__global__ __launch_bounds__(256) void prep_cw(const float* __restrict__ w,
                                               u16* __restrict__ wh,
                                               u16* __restrict__ wl) {
    const int K = CIN * 16;
    int idx = blockIdx.x * 256 + threadIdx.x;
    if (idx >= 128 * K) return;
    int co = idx / K, k = idx - co * K;
    int ic = k % CIN, s = k / CIN;
    int fy = s >> 2, fx = s & 3;
    u16 h, l;
    split2(w[((co * CIN + ic) * FS_ + fy) * FS_ + fx], h, l);
    wh[idx] = h; wl[idx] = l;
}

__global__ __launch_bounds__(256) void prep_mw(const float* __restrict__ w,
                                               u16* __restrict__ wh,
                                               u16* __restrict__ wl) {
    int idx = blockIdx.x * 256 + threadIdx.x;
    if (idx >= 128 * 128) return;
    int n = idx >> 7, k = idx & 127;
    u16 h, l;
    split2(w[k * 128 + n], h, l);
    wh[idx] = h; wl[idx] = l;
}

// ======================================================================
// split-bf16 MFMA GEMM (unchanged from R4)
// ======================================================================
template <int ASRC, int ABF, int OSTORE, bool RELU,
          int CIN, int HIN, int WIN, int HOUT, int WOUT>
__global__ __launch_bounds__(256, 2) void mgemm_k(const void* __restrict__ Ahv,
                                                  const void* __restrict__ Alv,
                                                  const u16* __restrict__ Bhg,
                                                  const u16* __restrict__ Blg,
                                                  const float* __restrict__ bias,
                                                  void* __restrict__ C0v,
                                                  void* __restrict__ C1v,
                                                  int Mrows, int K) {
    __shared__ u16 Ah_s[128 * 64];
    __shared__ u16 Al_s[128 * 64];
    __shared__ u16 Bh_s[128 * 64];
    __shared__ u16 Bl_s[128 * 64];

    const int tid = threadIdx.x;
    const int m0 = blockIdx.x * 128;
    const int wv = tid >> 6, lane = tid & 63;
    const int wm = wv >> 1, wn = wv & 1;
    const int lr = lane & 31;
    const int kh = lane >> 5;

    f32x16 acc[2][2];
#pragma unroll
    for (int i = 0; i < 2; ++i)
#pragma unroll
        for (int j = 0; j < 2; ++j)
#pragma unroll
            for (int r = 0; r < 16; ++r) acc[i][j][r] = 0.f;

    for (int k0 = 0; k0 < K; k0 += 64) {
#pragma unroll
        for (int g = 0; g < 4; ++g) {
            int gi = tid + g * 256;
            int row = gi >> 3, c = gi & 7;
            int m = m0 + row;
            if (m >= Mrows) m = Mrows - 1;
            int k = k0 + c * 8;
            size_t src;
            if constexpr (ASRC == 0) {
                src = (size_t)m * K + k;
            } else {
                int bb = m / (HOUT * WOUT), r = m % (HOUT * WOUT);
                int y = r / WOUT, xx = r % WOUT;
                int slice = k / CIN, ic = k - slice * CIN;
                int fy = slice >> 2, fx = slice & 3;
                src = ((size_t)((bb * HIN + y + fy) * WIN) + (xx + fx)) * CIN + ic;
            }
            int dst = row * 64 + ((c ^ (row & 7)) * 8);
            if constexpr (ABF == 1) {
                *(short8v*)&Ah_s[dst] = *(const short8v*)((const u16*)Ahv + src);
                *(short8v*)&Al_s[dst] = *(const short8v*)((const u16*)Alv + src);
            } else {
                const float* Af = (const float*)Ahv;
                float vv[8];
                *(float4*)&vv[0] = *(const float4*)&Af[src];
                *(float4*)&vv[4] = *(const float4*)&Af[src + 4];
                short8v hv, lv;
#pragma unroll
                for (int j = 0; j < 8; ++j) {
                    u16 h, l;
                    split2(vv[j], h, l);
                    hv[j] = (short)h; lv[j] = (short)l;
                }
                *(short8v*)&Ah_s[dst] = hv;
                *(short8v*)&Al_s[dst] = lv;
            }
        }
#pragma unroll
        for (int i = 0; i < 4; ++i) {
            int s = tid + i * 256;
            int nn = s >> 3, c = s & 7;
            size_t src = (size_t)nn * K + k0 + c * 8;
            int dst = nn * 64 + ((c ^ (nn & 7)) * 8);
            *(short8v*)&Bh_s[dst] = *(const short8v*)&Bhg[src];
            *(short8v*)&Bl_s[dst] = *(const short8v*)&Blg[src];
        }
        __syncthreads();
#pragma unroll
        for (int ks = 0; ks < 4; ++ks) {
            const int ch = ks * 2 + kh;
            short8v ah[2], al[2], bh[2], bl[2];
#pragma unroll
            for (int mf = 0; mf < 2; ++mf) {
                int row = wm * 64 + mf * 32 + lr;
                int idx = row * 64 + ((ch ^ (row & 7)) * 8);
                ah[mf] = *(const short8v*)&Ah_s[idx];
                al[mf] = *(const short8v*)&Al_s[idx];
            }
#pragma unroll
            for (int nf = 0; nf < 2; ++nf) {
                int rn = wn * 64 + nf * 32 + lr;
                int idx = rn * 64 + ((ch ^ (rn & 7)) * 8);
                bh[nf] = *(const short8v*)&Bh_s[idx];
                bl[nf] = *(const short8v*)&Bl_s[idx];
            }
#pragma unroll
            for (int mf = 0; mf < 2; ++mf)
#pragma unroll
                for (int nf = 0; nf < 2; ++nf) {
                    acc[mf][nf] = __builtin_amdgcn_mfma_f32_32x32x16_bf16(
                        ah[mf], bh[nf], acc[mf][nf], 0, 0, 0);
                    acc[mf][nf] = __builtin_amdgcn_mfma_f32_32x32x16_bf16(
                        ah[mf], bl[nf], acc[mf][nf], 0, 0, 0);
                    acc[mf][nf] = __builtin_amdgcn_mfma_f32_32x32x16_bf16(
                        al[mf], bh[nf], acc[mf][nf], 0, 0, 0);
                }
        }
        __syncthreads();
    }

#pragma unroll
    for (int mf = 0; mf < 2; ++mf)
#pragma unroll
        for (int nf = 0; nf < 2; ++nf) {
            int n = wn * 64 + nf * 32 + lr;
            float bv = bias[n];
#pragma unroll
            for (int r = 0; r < 16; ++r) {
                int row = (r & 3) + 8 * (r >> 2) + 4 * kh;
                int m = m0 + wm * 64 + mf * 32 + row;
                if (m >= Mrows) continue;
                float t = acc[mf][nf][r] + bv;
                if (RELU) t = fmaxf(t, 0.f);
                if constexpr (OSTORE == 0) {
                    ((float*)C0v)[(size_t)m * 128 + n] = t;
                } else if constexpr (OSTORE == 1) {
                    int b = m / L_, l = m - b * L_;
                    int h = n >> 6, d = n & 63;
                    ((float*)C0v)[(((size_t)(b * NH_ + h) * L_ + l) << 6) + d] = t;
                } else {
                    u16 h, l;
                    split2(t, h, l);
                    ((u16*)C0v)[(size_t)m * 128 + n] = h;
                    ((u16*)C1v)[(size_t)m * 128 + n] = l;
                }
            }
        }
}

// ======================================================================
// K transpose: Kt[bh][l][d] -> Kdt[bh][d][l]
// ======================================================================
__global__ __launch_bounds__(256) void xposeK_k(const float* __restrict__ Kt,
                                                float* __restrict__ Kdt) {
    __shared__ float tile[32][33];
    int l0 = blockIdx.x * 32, d0 = blockIdx.y * 32, bh = blockIdx.z;
    int col = threadIdx.x & 31, rw = threadIdx.x >> 5;
#pragma unroll
    for (int r = 0; r < 4; ++r) {
        int l = l0 + rw + r * 8;
        if (l < L_) tile[rw + r * 8][col] = Kt[((size_t)bh * L_ + l) * 64 + d0 + col];
    }
    __syncthreads();
#pragma unroll
    for (int r = 0; r < 4; ++r) {
        int d = rw + r * 8;
        int l = l0 + col;
        if (l < L_) Kdt[((size_t)bh * 64 + d0 + d) * L_ + l] = tile[col][d];
    }
}

// ======================================================================
// probscore v4 (as R7): 8 uh-lanes shuffle-combine, one M[gl] write
// ======================================================================
__global__ __launch_bounds__(256) void probscore4_k(const float* __restrict__ Q,
                                                    const float* __restrict__ Kt,
                                                    const int* __restrict__ idxs,
                                                    float* __restrict__ Mout) {
    int bh = blockIdx.x;
    int l  = blockIdx.y * 32 + (threadIdx.x >> 3);
    int uh = threadIdx.x & 7;
    if (l >= L_) return;
    int gl = bh * L_ + l;

    int idxr[5];
#pragma unroll
    for (int j = 0; j < 5; ++j) idxr[j] = idxs[l * U_ + uh * 5 + j];

    const float4* Q4  = (const float4*)Q + (size_t)gl * 16;
    const float4* Kb4 = (const float4*)Kt + (size_t)bh * L_ * 16;

    float acc[5];
#pragma unroll
    for (int j = 0; j < 5; ++j) acc[j] = 0.f;

#pragma unroll
    for (int dc = 0; dc < 4; ++dc) {
        float4 q0 = Q4[dc * 4 + 0];
        float4 q1 = Q4[dc * 4 + 1];
        float4 q2 = Q4[dc * 4 + 2];
        float4 q3 = Q4[dc * 4 + 3];
#pragma unroll
        for (int j = 0; j < 5; ++j) {
            const float4* kr = Kb4 + (size_t)idxr[j] * 16 + dc * 4;
            float4 a = kr[0], b = kr[1], c = kr[2], d = kr[3];
            float t = acc[j];
            t = fmaf(q0.x, a.x, t); t = fmaf(q0.y, a.y, t);
            t = fmaf(q0.z, a.z, t); t = fmaf(q0.w, a.w, t);
            t = fmaf(q1.x, b.x, t); t = fmaf(q1.y, b.y, t);
            t = fmaf(q1.z, b.z, t); t = fmaf(q1.w, b.w, t);
            t = fmaf(q2.x, c.x, t); t = fmaf(q2.y, c.y, t);
            t = fmaf(q2.z, c.z, t); t = fmaf(q2.w, c.w, t);
            t = fmaf(q3.x, d.x, t); t = fmaf(q3.y, d.y, t);
            t = fmaf(q3.z, d.z, t); t = fmaf(q3.w, d.w, t);
            acc[j] = t;
        }
    }
    float mx = -1e30f, sm = 0.f;
#pragma unroll
    for (int j = 0; j < 5; ++j) { mx = fmaxf(mx, acc[j]); sm += acc[j]; }
#pragma unroll
    for (int o = 1; o < 8; o <<= 1) {
        mx = fmaxf(mx, __shfl_xor(mx, o));
        sm += __shfl_xor(sm, o);
    }
    if (uh == 0) Mout[gl] = mx - sm * (1.0f / (float)L_);
}

// ======================================================================
// topk v2 (as R7): register-sorted keys, shuffle-argmax extraction
// ======================================================================
__global__ __launch_bounds__(64) void topk2_k(const float* __restrict__ M,
                                              int* __restrict__ Mtop) {
    __shared__ u64 sk[24][64];
    int bh = blockIdx.x, lane = threadIdx.x;

    u64 k[24];
#pragma unroll
    for (int p = 0; p < 24; ++p) {
        int el = p * 64 + lane;          // coalesced
        u64 key = 0ULL;
        if (el < L_) {
            unsigned u = __float_as_uint(M[bh * L_ + el]);
            u ^= (u & 0x80000000u) ? 0xFFFFFFFFu : 0x80000000u;   // order-preserving
            key = ((u64)u << 32) | (unsigned)(~el);
        }
        k[p] = key;
    }
#pragma unroll
    for (int ph = 0; ph < 24; ++ph) {
#pragma unroll
        for (int j0 = 0; j0 < 12; ++j0) {
            int j = j0 * 2 + (ph & 1);
            if (j + 1 < 24) {
                u64 a = k[j], b = k[j + 1];
                k[j]     = a > b ? a : b;
                k[j + 1] = a > b ? b : a;
            }
        }
    }
#pragma unroll
    for (int p = 0; p < 24; ++p) sk[p][lane] = k[p];

    u64 cur = k[0];
    int ptr = 0;
    for (int it = 0; it < U_; ++it) {
        u64 best = cur; int bl = lane;
#pragma unroll
        for (int o = 32; o >= 1; o >>= 1) {
            u64 ok = __shfl_xor(best, o);
            int ol = __shfl_xor(bl, o);
            if (ok > best) { best = ok; bl = ol; }
        }
        if (lane == 0) Mtop[bh * U_ + it] = (int)(~(unsigned)best);
        if (lane == bl) {
            ++ptr;
            cur = (ptr < 24) ? sk[ptr][lane] : 0ULL;
        }
    }
}

// ======================================================================
// Vmean + ctx fill (unchanged)
// ======================================================================
__global__ __launch_bounds__(256) void vmean_k(const float* __restrict__ V,
                                               float* __restrict__ Vm) {
    __shared__ float red[256];
    int bh = blockIdx.x;
    int d = threadIdx.x & 63, part = threadIdx.x >> 6;
    const float* Vb = V + (size_t)bh * L_ * 64;
    float s = 0.f;
    for (int l = part; l < L_; l += 4) s += Vb[l * 64 + d];
    red[threadIdx.x] = s;
    __syncthreads();
    if (part == 0) {
        s = red[d] + red[64 + d] + red[128 + d] + red[192 + d];
        Vm[bh * 64 + d] = s / (float)L_;
    }
}

__global__ __launch_bounds__(256) void fill_ctx_k(const float* __restrict__ Vm,
                                                  float* __restrict__ ctxp) {
    int idx = blockIdx.x * 256 + threadIdx.x;
    if (idx >= B_ * L_ * 32) return;
    int c4 = idx & 31;
    int bl = idx >> 5;
    int b = bl / L_;
    int h = c4 >> 4, d4 = (c4 & 15) * 4;
    float4 v = *(const float4*)&Vm[(b * 2 + h) * 64 + d4];
    *(float4*)&ctxp[(size_t)idx * 4] = v;
}

// ======================================================================
// attn v4: 4 queries per block (grid 320 = 32 bh x 10 ugroups).
// Decode bh = bid & 31 keeps XCD = bh%8 (K/V L2-resident, 4 bh = 3MB/XCD).
// Each K4/V element loaded ONCE per block serves 4 queries: L2 traffic
// 988MB -> 247MB vs 1-query blocks.
// ======================================================================
__global__ __launch_bounds__(256) void attn4_k(const float* __restrict__ Q,
                                               const float* __restrict__ Kdt,
                                               const float* __restrict__ V,
                                               const int* __restrict__ Mtop,
                                               float* __restrict__ ctxp) {
    __shared__ float4 s4buf[4][L4_];     // 24.1KB score buffers
    __shared__ float qs[4][64];
    __shared__ float red4[256 * 4];
    __shared__ float bcast[8];           // [0..3] max, [4..7] inv-sum

    int tid = threadIdx.x;
    int bid = blockIdx.x;
    int bh = bid & 31, ug = bid >> 5;    // XCD-local: XCD = bh%8
    int b = bh >> 1, h = bh & 1;

    int qi[4];
#pragma unroll
    for (int j = 0; j < 4; ++j) qi[j] = Mtop[bh * U_ + ug * 4 + j];

    if (tid < 64) {
        int j = tid >> 4, q4 = tid & 15;
        ((float4*)qs[j])[q4] = ((const float4*)Q)[((size_t)bh * L_ + qi[j]) * 16 + q4];
    }
    __syncthreads();

    // ---- scores: thread per float4-of-l, 4 queries per K load ----
    const float4* K4 = (const float4*)Kdt + (size_t)bh * 64 * L4_;
    float mx[4] = {-1e30f, -1e30f, -1e30f, -1e30f};
    for (int s4i = tid; s4i < L4_; s4i += 256) {
        float4 a0 = {0.f,0.f,0.f,0.f}, a1 = a0, a2 = a0, a3 = a0;
#pragma unroll 8
        for (int d = 0; d < 64; ++d) {
            float4 k4 = K4[(size_t)d * L4_ + s4i];
            float q0 = qs[0][d], q1 = qs[1][d], q2 = qs[2][d], q3 = qs[3][d];
            a0.x = fmaf(q0, k4.x, a0.x); a0.y = fmaf(q0, k4.y, a0.y);
            a0.z = fmaf(q0, k4.z, a0.z); a0.w = fmaf(q0, k4.w, a0.w);
            a1.x = fmaf(q1, k4.x, a1.x); a1.y = fmaf(q1, k4.y, a1.y);
            a1.z = fmaf(q1, k4.z, a1.z); a1.w = fmaf(q1, k4.w, a1.w);
            a2.x = fmaf(q2, k4.x, a2.x); a2.y = fmaf(q2, k4.y, a2.y);
            a2.z = fmaf(q2, k4.z, a2.z); a2.w = fmaf(q2, k4.w, a2.w);
            a3.x = fmaf(q3, k4.x, a3.x); a3.y = fmaf(q3, k4.y, a3.y);
            a3.z = fmaf(q3, k4.z, a3.z); a3.w = fmaf(q3, k4.w, a3.w);
        }
        float4 av[4] = {a0, a1, a2, a3};
#pragma unroll
        for (int j = 0; j < 4; ++j) {
            float4 a = av[j];
            a.x *= 0.125f; a.y *= 0.125f; a.z *= 0.125f; a.w *= 0.125f;
            s4buf[j][s4i] = a;
            mx[j] = fmaxf(mx[j], fmaxf(fmaxf(a.x, a.y), fmaxf(a.z, a.w)));
        }
    }
#pragma unroll
    for (int j = 0; j < 4; ++j) red4[tid * 4 + j] = mx[j];
    __syncthreads();
    {   // wave w reduces query w's max
        int w = tid >> 6, lane = tid & 63;
        float m4 = fmaxf(fmaxf(red4[lane * 4 + w], red4[(lane + 64) * 4 + w]),
                         fmaxf(red4[(lane + 128) * 4 + w], red4[(lane + 192) * 4 + w]));
#pragma unroll
        for (int o = 32; o >= 1; o >>= 1) m4 = fmaxf(m4, __shfl_xor(m4, o));
        if (lane == 0) bcast[w] = m4;
    }
    __syncthreads();
    float bmx0 = bcast[0], bmx1 = bcast[1], bmx2 = bcast[2], bmx3 = bcast[3];

    // ---- exp + sum ----
    float ps[4] = {0.f, 0.f, 0.f, 0.f};
    float* s0 = (float*)s4buf[0];
    float* s1 = (float*)s4buf[1];
    float* s2 = (float*)s4buf[2];
    float* s3 = (float*)s4buf[3];
    for (int l = tid; l < L_; l += 256) {
        float e0 = __expf(s0[l] - bmx0); s0[l] = e0; ps[0] += e0;
        float e1 = __expf(s1[l] - bmx1); s1[l] = e1; ps[1] += e1;
        float e2 = __expf(s2[l] - bmx2); s2[l] = e2; ps[2] += e2;
        float e3 = __expf(s3[l] - bmx3); s3[l] = e3; ps[3] += e3;
    }
#pragma unroll
    for (int j = 0; j < 4; ++j) red4[tid * 4 + j] = ps[j];
    __syncthreads();
    {   // wave w reduces query w's sum
        int w = tid >> 6, lane = tid & 63;
        float sm = red4[lane * 4 + w] + red4[(lane + 64) * 4 + w] +
                   red4[(lane + 128) * 4 + w] + red4[(lane + 192) * 4 + w];
#pragma unroll
        for (int o = 32; o >= 1; o >>= 1) sm += __shfl_xor(sm, o);
        if (lane == 0) bcast[4 + w] = 1.0f / sm;
    }
    __syncthreads();

    // ---- PV: wave w handles l = w mod 4, lane = d; V loaded once for 4 q ----
    int w = tid >> 6, lane = tid & 63;
    const float* Vb = V + (size_t)bh * L_ * 64;
    float pacc[4] = {0.f, 0.f, 0.f, 0.f};
    for (int l = w; l < L_; l += 4) {
        float vv = Vb[(size_t)l * 64 + lane];
        pacc[0] = fmaf(s0[l], vv, pacc[0]);
        pacc[1] = fmaf(s1[l], vv, pacc[1]);
        pacc[2] = fmaf(s2[l], vv, pacc[2]);
        pacc[3] = fmaf(s3[l], vv, pacc[3]);
    }
#pragma unroll
    for (int j = 0; j < 4; ++j) red4[tid * 4 + j] = pacc[j];
    __syncthreads();
    if (w == 0) {
#pragma unroll
        for (int j = 0; j < 4; ++j) {
            float r = red4[lane * 4 + j] + red4[(lane + 64) * 4 + j] +
                      red4[(lane + 128) * 4 + j] + red4[(lane + 192) * 4 + j];
            ctxp[((size_t)b * L_ + qi[j]) * 128 + h * 64 + lane] = r * bcast[4 + j];
        }
    }
}

// ======================================================================
// launch
// ======================================================================
extern "C" void kernel_launch(void* const* d_in, const int* in_sizes, int n_in,
                              void* d_out, int out_size, void* d_ws, size_t ws_size,
                              hipStream_t stream) {
    const float* x   = (const float*)d_in[0];
    const float* c1w = (const float*)d_in[1];
    const float* c1b = (const float*)d_in[2];
    const float* c2w = (const float*)d_in[3];
    const float* c2b = (const float*)d_in[4];
    const float* wq  = (const float*)d_in[5];
    const float* bq  = (const float*)d_in[6];
    const float* wk  = (const float*)d_in[7];
    const float* bk  = (const float*)d_in[8];
    const float* wv  = (const float*)d_in[9];
    const float* bv  = (const float*)d_in[10];
    const float* wo  = (const float*)d_in[11];
    const float* bo  = (const float*)d_in[12];
    const int* isamp = (const int*)d_in[13];
    float* out = (float*)d_out;

    char* cur = (char*)d_ws;
    auto alloc = [&](size_t bytes) {
        char* p = cur;
        cur += (bytes + 255) & ~(size_t)255;
        return p;
    };
    u16* xp_h  = (u16*)alloc(524288 * 2);
    u16* xp_l  = (u16*)alloc(524288 * 2);
    u16* wt1h  = (u16*)alloc(32768 * 2);
    u16* wt1l  = (u16*)alloc(32768 * 2);
    u16* wt2h  = (u16*)alloc(262144 * 2);
    u16* wt2l  = (u16*)alloc(262144 * 2);
    u16* wtqh  = (u16*)alloc(16384 * 2);
    u16* wtql  = (u16*)alloc(16384 * 2);
    u16* wtkh  = (u16*)alloc(16384 * 2);
    u16* wtkl  = (u16*)alloc(16384 * 2);
    u16* wtvh  = (u16*)alloc(16384 * 2);
    u16* wtvl  = (u16*)alloc(16384 * 2);
    u16* wtoh  = (u16*)alloc(16384 * 2);
    u16* wtol  = (u16*)alloc(16384 * 2);
    u16* h1_h  = (u16*)alloc(3622912 * 2);
    u16* h1_l  = (u16*)alloc(3622912 * 2);
    u16* seq_h = (u16*)alloc(3088384 * 2);
    u16* seq_l = (u16*)alloc(3088384 * 2);
    float* Q    = (float*)alloc(3088384 * 4);
    float* Kt   = (float*)alloc(3088384 * 4);
    float* V    = (float*)alloc(3088384 * 4);
    float* Vm   = (float*)alloc(2048 * 4);
    float* ctxp = (float*)alloc(3088384 * 4);
    int*   Mtop = (int*)alloc(1280 * 4);
    float* Kdt  = (float*)h1_h;          // alias: h1 dead after conv2
    float* Mp   = (float*)seq_h;         // alias: seq dead after projections

    xpose_x_split<<<2048, 256, 0, stream>>>(x, xp_h, xp_l);
    prep_cw<16><<<128, 256, 0, stream>>>(c1w, wt1h, wt1l);
    prep_cw<128><<<1024, 256, 0, stream>>>(c2w, wt2h, wt2l);
    prep_mw<<<64, 256, 0, stream>>>(wq, wtqh, wtql);
    prep_mw<<<64, 256, 0, stream>>>(wk, wtkh, wtkl);
    prep_mw<<<64, 256, 0, stream>>>(wv, wtvh, wtvl);
    prep_mw<<<64, 256, 0, stream>>>(wo, wtoh, wtol);

    mgemm_k<1, 1, 2, true, 16, 64, 32, 61, 29>
        <<<222, 256, 0, stream>>>(xp_h, xp_l, wt1h, wt1l, c1b, h1_h, h1_l, M1_, 256);
    mgemm_k<1, 1, 2, true, 128, 61, 29, 58, 26>
        <<<189, 256, 0, stream>>>(h1_h, h1_l, wt2h, wt2l, c2b, seq_h, seq_l, M2_, 2048);

    mgemm_k<0, 1, 1, false, 1, 1, 1, 1, 1>
        <<<189, 256, 0, stream>>>(seq_h, seq_l, wtqh, wtql, bq, Q, nullptr, M2_, 128);
    mgemm_k<0, 1, 1, false, 1, 1, 1, 1, 1>
        <<<189, 256, 0, stream>>>(seq_h, seq_l, wtkh, wtkl, bk, Kt, nullptr, M2_, 128);
    mgemm_k<0, 1, 1, false, 1, 1, 1, 1, 1>
        <<<189, 256, 0, stream>>>(seq_h, seq_l, wtvh, wtvl, bv, V, nullptr, M2_, 128);

    xposeK_k<<<dim3(48, 2, 32), 256, 0, stream>>>(Kt, Kdt);
    probscore4_k<<<dim3(32, 48), 256, 0, stream>>>(Q, Kt, isamp, Mp);
    topk2_k<<<32, 64, 0, stream>>>(Mp, Mtop);
    vmean_k<<<32, 256, 0, stream>>>(V, Vm);
    fill_ctx_k<<<3016, 256, 0, stream>>>(Vm, ctxp);
    attn4_k<<<320, 256, 0, stream>>>(Q, Kdt, V, Mtop, ctxp);

    mgemm_k<0, 0, 0, false, 1, 1, 1, 1, 1>
        <<<189, 256, 0, stream>>>(ctxp, nullptr, wtoh, wtol, bo, out, nullptr, M2_, 128);
}